// Round 2
// baseline (2418.908 us; speedup 1.0000x reference)
//
#include <hip/hip_runtime.h>
#include <math.h>

#define EN   768
#define BN   4
#define SN   1024
#define HN   12
#define BSN  4096          // B*S
#define BSE  3145728       // B*S*E

// ---- workspace layout (floats) ----  total 15,739,907 floats = 63.0 MB
#define OFF_MQ   0
#define OFF_MK   3145728
#define OFF_MV   6291456
#define OFF_MUC  9437184
#define OFF_SGC  12582912
#define OFF_XX   15728640   // [4096]
#define OFF_RC   15732736   // [4096]
#define OFF_WS   15736832   // [4][768] softplus(w_sigma) for q,k,v,o
#define OFF_KL   15739904   // [3]: Smu2, Ssig, Ssp

__device__ __forceinline__ float sp_f(float x){
  // numerically stable softplus, matches jax.nn.softplus / log1p(exp(x))
  return fmaxf(x, 0.f) + log1pf(__expf(-fabsf(x)));
}

__device__ __forceinline__ float blk_reduce(float v, float* tmp){
  #pragma unroll
  for (int off = 32; off; off >>= 1) v += __shfl_down(v, off, 64);
  int w = threadIdx.x >> 6;
  if ((threadIdx.x & 63) == 0) tmp[w] = v;
  __syncthreads();
  float r = 0.f;
  if (threadIdx.x == 0) r = tmp[0] + tmp[1] + tmp[2] + tmp[3];
  __syncthreads();
  return r;
}

// ---- softplus(w_sigma) vectors + KL sigma-terms ----
__global__ void k_prep(const float* __restrict__ s0, const float* __restrict__ s1,
                       const float* __restrict__ s2, const float* __restrict__ s3,
                       float* __restrict__ wsig, float* __restrict__ klacc){
  __shared__ float tmp[4];
  const float* src = (blockIdx.x == 0) ? s0 : (blockIdx.x == 1) ? s1 : (blockIdx.x == 2) ? s2 : s3;
  int l = blockIdx.x;
  float ssum = 0.f, spsum = 0.f;
  for (int j = threadIdx.x; j < EN; j += 256){
    float sg = src[j];
    float w  = log1pf(__expf(sg));     // sg in [-4.6,-2.25]: exp safe
    wsig[l*EN + j] = w;
    ssum += sg; spsum += w;
  }
  float a = blk_reduce(ssum, tmp);
  float b = blk_reduce(spsum, tmp);
  if (threadIdx.x == 0){ atomicAdd(&klacc[1], a); atomicAdd(&klacc[2], b); }
}

// ---- xx[r] = sum_e (x/768)^2 ----
__global__ void k_xx(const float* __restrict__ x, float* __restrict__ xx){
  __shared__ float tmp[4];
  int r = blockIdx.x;
  const float* xr = x + (long)r*EN;
  float s = 0.f;
  for (int j = threadIdx.x; j < EN; j += 256){ float v = xr[j]; s += v*v; }
  float t = blk_reduce(s, tmp);
  if (threadIdx.x == 0) xx[r] = t * (1.0f/589824.0f);
}

// ---- sum of mu^2 over the four weight matrices ----
__global__ void k_mu2(const float* __restrict__ w0, const float* __restrict__ w1,
                      const float* __restrict__ w2, const float* __restrict__ w3,
                      float* __restrict__ klacc){
  __shared__ float tmp[4];
  const float* w = (blockIdx.y == 0) ? w0 : (blockIdx.y == 1) ? w1 : (blockIdx.y == 2) ? w2 : w3;
  const float4* w4 = (const float4*)w;
  float s = 0.f;
  for (int i = blockIdx.x*256 + threadIdx.x; i < 147456; i += gridDim.x*256){
    float4 v = w4[i];
    s += v.x*v.x + v.y*v.y + v.z*v.z + v.w*v.w;
  }
  float r = blk_reduce(s, tmp);
  if (threadIdx.x == 0) atomicAdd(&klacc[0], r);
}

// ---- projections: out = x @ W  (64x128 tile, 4x8 micro) ----
__global__ __launch_bounds__(256)
void k_proj(const float* __restrict__ x, const float* __restrict__ wq,
            const float* __restrict__ wk, const float* __restrict__ wv,
            float* __restrict__ mq, float* __restrict__ mk, float* __restrict__ mv){
  __shared__ float Ax[64*65];
  __shared__ float Bw[64*128];
  const float* W; float* out;
  if (blockIdx.z == 0){ W = wq; out = mq; }
  else if (blockIdx.z == 1){ W = wk; out = mk; }
  else { W = wv; out = mv; }
  int tid = threadIdx.x, tx = tid & 15, ty = tid >> 4;
  int r0 = blockIdx.y*64, c0 = blockIdx.x*128;
  float acc[4][8];
  for (int i=0;i<4;++i)
    for (int j=0;j<8;++j) acc[i][j]=0.f;
  for (int e0 = 0; e0 < EN; e0 += 64){
    __syncthreads();
    #pragma unroll
    for (int it=0; it<16; ++it){ int idx=it*256+tid; int r=idx>>6, e=idx&63;
      Ax[r*65+e] = x[(long)(r0+r)*EN + e0+e]; }
    #pragma unroll
    for (int it=0; it<32; ++it){ int idx=it*256+tid; int e=idx>>7, c=idx&127;
      Bw[e*128+c] = W[(long)(e0+e)*EN + c0+c]; }
    __syncthreads();
    #pragma unroll 8
    for (int ee=0; ee<64; ++ee){
      float a[4];
      #pragma unroll
      for (int i=0;i<4;++i) a[i] = Ax[(ty*4+i)*65 + ee];
      float4 b0 = *(const float4*)&Bw[ee*128 + tx*8];
      float4 b1 = *(const float4*)&Bw[ee*128 + tx*8 + 4];
      float bb[8] = {b0.x,b0.y,b0.z,b0.w,b1.x,b1.y,b1.z,b1.w};
      #pragma unroll
      for (int i=0;i<4;++i)
        #pragma unroll
        for (int j=0;j<8;++j) acc[i][j] = fmaf(a[i], bb[j], acc[i][j]);
    }
  }
  #pragma unroll
  for (int i=0;i<4;++i){
    float4 o0 = {acc[i][0],acc[i][1],acc[i][2],acc[i][3]};
    float4 o1 = {acc[i][4],acc[i][5],acc[i][6],acc[i][7]};
    long base = (long)(r0+ty*4+i)*EN + c0 + tx*8;
    *(float4*)&out[base]   = o0;
    *(float4*)&out[base+4] = o1;
  }
}

// ---- fused Bayesian attention per (q-tile, h, b) ----
// dynamic LDS: 29376 floats = 117504 B
__global__ __launch_bounds__(256, 1)
void k_attn(const float* __restrict__ mqp, const float* __restrict__ mkp,
            const float* __restrict__ mvp, const float* __restrict__ xx,
            const float* __restrict__ wsig, float* __restrict__ mu_cat,
            float* __restrict__ sig_cat){
  extern __shared__ float lds[];
  float* A_mq  = lds;            // [64][65] mq rows (q)
  float* A_cb  = lds + 4160;     // mq^2 + sq   (rows q)
  float* A_mk2 = lds + 8320;     // mk^2        (rows q!)
  float* U     = lds + 12480;    // union region
  float* Bmk   = U;              // [64 d][68 k]
  float* Bsk   = U + 4352;       // sk/64, d-major
  float* Bsq   = U + 8704;       // sq/64, d-major
  float* P_W   = U;              // [64 q][65 k]
  float* P_G   = U + 4160;       // Sw
  float* Vmv   = U + 8320;       // [64 k][64 d]
  float* Vsv   = U + 12416;      // [64 k][64 d]
  float* s_xxq = lds + 28992;    // [64]
  float* s_xxk = s_xxq + 64;
  float* s_wq  = s_xxq + 128;
  float* s_wk  = s_xxq + 192;
  float* s_wv  = s_xxq + 256;
  float* s_Z   = s_xxq + 320;    // [64]

  const int tid = threadIdx.x;
  const int tx = tid & 15, ty = tid >> 4;
  const int q0 = blockIdx.x * 64;
  const int h  = blockIdx.y;
  const int b  = blockIdx.z;
  const long base = (long)b * SN;

  if (tid < 64){
    s_xxq[tid] = xx[b*SN + q0 + tid];
    s_wq[tid]  = wsig[0*EN + h*64 + tid];
    s_wk[tid]  = wsig[1*EN + h*64 + tid];
    s_wv[tid]  = wsig[2*EN + h*64 + tid];
  }
  __syncthreads();
  {
    const float* mqg = mqp + (base + q0)*EN + h*64;
    const float* mkg = mkp + (base + q0)*EN + h*64;
    #pragma unroll
    for (int it=0; it<16; ++it){
      int idx = it*256 + tid; int r = idx>>6, c = idx&63;
      float vq = mqg[(long)r*EN + c];
      float vk = mkg[(long)r*EN + c];
      float sq = sp_f(s_xxq[r] * s_wq[c]);
      A_mq[r*65+c]  = vq;
      A_cb[r*65+c]  = fmaf(vq, vq, sq);
      A_mk2[r*65+c] = vk*vk;
    }
  }

  // ---- pass 1: softmax denominator Z (no max subtraction needed; |mu/8| < ~7) ----
  float zpart[4] = {0.f,0.f,0.f,0.f};
  for (int kt=0; kt<16; ++kt){
    const float* mkg = mkp + (base + kt*64)*EN + h*64;
    __syncthreads();
    #pragma unroll
    for (int it=0; it<16; ++it){
      int idx=it*256+tid; int r=idx>>6, c=idx&63;
      Bmk[c*68 + r] = mkg[(long)r*EN + c];
    }
    __syncthreads();
    float mu[4][4] = {{0.f}};
    #pragma unroll 8
    for (int d=0; d<64; ++d){
      float aq[4];
      #pragma unroll
      for (int i=0;i<4;++i) aq[i] = A_mq[(ty*4+i)*65 + d];
      float4 b4 = *(const float4*)&Bmk[d*68 + tx*4];
      float bk[4] = {b4.x,b4.y,b4.z,b4.w};
      #pragma unroll
      for (int i=0;i<4;++i)
        #pragma unroll
        for (int j=0;j<4;++j) mu[i][j] = fmaf(aq[i], bk[j], mu[i][j]);
    }
    #pragma unroll
    for (int i=0;i<4;++i)
      #pragma unroll
      for (int j=0;j<4;++j) zpart[i] += __expf(mu[i][j]*0.125f);
  }
  #pragma unroll
  for (int off=8; off; off>>=1){
    #pragma unroll
    for (int i=0;i<4;++i) zpart[i] += __shfl_down(zpart[i], off, 16);
  }
  if (tx == 0){
    #pragma unroll
    for (int i=0;i<4;++i) s_Z[ty*4+i] = zpart[i];
  }
  __syncthreads();
  float zinv[4];
  #pragma unroll
  for (int i=0;i<4;++i) zinv[i] = 1.0f / s_Z[ty*4+i];

  // ---- pass 2: scores -> w, Sw -> 3 PV accumulations ----
  float accM[4][4]={{0.f}}, accD[4][4]={{0.f}}, accE[4][4]={{0.f}};
  for (int kt=0; kt<16; ++kt){
    const long kb = base + kt*64;
    const float* mkg = mkp + kb*EN + h*64;
    const float* mvg = mvp + kb*EN + h*64;
    __syncthreads();                              // prev PV readers done
    if (tid < 64) s_xxk[tid] = xx[b*SN + kt*64 + tid];
    #pragma unroll
    for (int it=0; it<16; ++it){
      int idx=it*256+tid; int r=idx>>6, c=idx&63;
      Bmk[c*68+r] = mkg[(long)r*EN + c];
    }
    __syncthreads();                              // s_xxk ready
    #pragma unroll
    for (int it=0; it<16; ++it){
      int idx=it*256+tid; int r=idx>>6, c=idx&63;
      float xk = s_xxk[r];
      Bsk[c*68+r] = sp_f(xk * s_wk[c]) * (1.0f/64.0f);
      Bsq[c*68+r] = sp_f(xk * s_wq[c]) * (1.0f/64.0f);
    }
    __syncthreads();                              // all B tiles ready
    float mu[4][4]={{0.f}}, sg[4][4]={{0.f}};
    #pragma unroll 8
    for (int d=0; d<64; ++d){
      float aq[4], ac[4], am[4];
      #pragma unroll
      for (int i=0;i<4;++i){
        int ro = (ty*4+i)*65 + d;
        aq[i]=A_mq[ro]; ac[i]=A_cb[ro]; am[i]=A_mk2[ro];
      }
      float4 b1 = *(const float4*)&Bmk[d*68 + tx*4];
      float4 b2 = *(const float4*)&Bsk[d*68 + tx*4];
      float4 b3 = *(const float4*)&Bsq[d*68 + tx*4];
      float bk[4]={b1.x,b1.y,b1.z,b1.w};
      float bs[4]={b2.x,b2.y,b2.z,b2.w};
      float bq[4]={b3.x,b3.y,b3.z,b3.w};
      #pragma unroll
      for (int i=0;i<4;++i)
        #pragma unroll
        for (int j=0;j<4;++j){
          mu[i][j] = fmaf(aq[i], bk[j], mu[i][j]);
          sg[i][j] = fmaf(ac[i], bs[j], sg[i][j]);   // a + c terms
          sg[i][j] = fmaf(am[i], bq[j], sg[i][j]);   // b term
        }
    }
    __syncthreads();                              // B reads done: U reusable
    #pragma unroll
    for (int i=0;i<4;++i)
      #pragma unroll
      for (int j=0;j<4;++j){
        float e = __expf(mu[i][j]*0.125f);
        float w = e * zinv[i];
        float u = w - w*w;
        int pidx = (ty*4+i)*65 + tx*4+j;
        P_W[pidx] = w;
        // Sw = grad * (sigma_score/64) / 1024
        P_G[pidx] = (u*u) * sg[i][j] * (1.0f/65536.0f);
      }
    #pragma unroll
    for (int it=0; it<16; ++it){
      int idx=it*256+tid; int r=idx>>6, c=idx&63;
      Vmv[r*64+c] = mvg[(long)r*EN + c];
      Vsv[r*64+c] = sp_f(s_xxk[r] * s_wv[c]);
    }
    __syncthreads();                              // P,V ready
    #pragma unroll 8
    for (int kk=0; kk<64; ++kk){
      float pw[4], pg[4];
      #pragma unroll
      for (int i=0;i<4;++i){
        int ro=(ty*4+i)*65+kk;
        pw[i]=P_W[ro]; pg[i]=P_G[ro];
      }
      float4 v1=*(const float4*)&Vmv[kk*64+tx*4];
      float4 v2=*(const float4*)&Vsv[kk*64+tx*4];
      float vm[4]={v1.x,v1.y,v1.z,v1.w};
      float vs[4]={v2.x,v2.y,v2.z,v2.w};
      float vc[4], pw2[4];
      #pragma unroll
      for (int j=0;j<4;++j) vc[j] = fmaf(vm[j], vm[j], vs[j]);  // mv^2+sv
      #pragma unroll
      for (int i=0;i<4;++i) pw2[i] = pw[i]*pw[i];
      #pragma unroll
      for (int i=0;i<4;++i)
        #pragma unroll
        for (int j=0;j<4;++j){
          accM[i][j] = fmaf(pw[i],  vm[j], accM[i][j]);
          accD[i][j] = fmaf(pw2[i], vs[j], accD[i][j]);
          accE[i][j] = fmaf(pg[i],  vc[j], accE[i][j]);
        }
    }
  }
  #pragma unroll
  for (int i=0;i<4;++i){
    long orow = (base + q0 + ty*4 + i)*EN + h*64 + tx*4;
    float4 m4 = {accM[i][0],accM[i][1],accM[i][2],accM[i][3]};
    float4 s4;
    s4.x = sp_f((accD[i][0]+accE[i][0])*(1.0f/1024.0f));
    s4.y = sp_f((accD[i][1]+accE[i][1])*(1.0f/1024.0f));
    s4.z = sp_f((accD[i][2]+accE[i][2])*(1.0f/1024.0f));
    s4.w = sp_f((accD[i][3]+accE[i][3])*(1.0f/1024.0f));
    *(float4*)&mu_cat[orow]  = m4;
    *(float4*)&sig_cat[orow] = s4;
  }
}

// ---- per-row combined scalar for S2+S3 ----
__global__ void k_rows(const float* __restrict__ mu_cat, const float* __restrict__ sg_cat,
                       float* __restrict__ rcomb){
  __shared__ float tmp[4];
  int r = blockIdx.x;
  const float* m = mu_cat + (long)r*EN;
  const float* s = sg_cat + (long)r*EN;
  float s1 = 0.f, s2 = 0.f;
  for (int j = threadIdx.x; j < EN; j += 256){ float a = m[j]; s1 += a*a; s2 += s[j]; }
  float r1 = blk_reduce(s1, tmp);
  float r2 = blk_reduce(s2, tmp);
  if (threadIdx.x == 0) rcomb[r] = r1*(1.0f/589824.0f) + r2*(1.0f/768.0f);
}

// ---- output linear with fused Sigma epilogue (64x128 tile, Kc=32) ----
__global__ __launch_bounds__(256)
void k_out(const float* __restrict__ mu_cat, const float* __restrict__ sg_cat,
           const float* __restrict__ wo, const float* __restrict__ rcomb,
           const float* __restrict__ wso, float* __restrict__ mu_out,
           float* __restrict__ sg_out){
  __shared__ float Am[64*33], As[64*33], Bw[32*128], B2[32*128];
  int tid = threadIdx.x, tx = tid & 15, ty = tid >> 4;
  int r0 = blockIdx.y*64, c0 = blockIdx.x*128;
  float accM[4][8], accS[4][8];
  for (int i=0;i<4;++i)
    for (int j=0;j<8;++j){ accM[i][j]=0.f; accS[i][j]=0.f; }
  for (int e0 = 0; e0 < EN; e0 += 32){
    __syncthreads();
    #pragma unroll
    for (int it=0; it<8; ++it){ int idx=it*256+tid; int r=idx>>5, e=idx&31;
      Am[r*33+e] = mu_cat[(long)(r0+r)*EN + e0+e];
      As[r*33+e] = sg_cat[(long)(r0+r)*EN + e0+e]; }
    #pragma unroll
    for (int it=0; it<16; ++it){ int idx=it*256+tid; int e=idx>>7, c=idx&127;
      float w = wo[(long)(e0+e)*EN + c0+c];
      Bw[e*128+c] = w;
      B2[e*128+c] = w*w*(1.0f/768.0f); }   // (wo/sqrt(768))^2
    __syncthreads();
    #pragma unroll 8
    for (int ee=0; ee<32; ++ee){
      float am[4], as_[4];
      #pragma unroll
      for (int i=0;i<4;++i){ int ro=(ty*4+i)*33+ee; am[i]=Am[ro]; as_[i]=As[ro]; }
      float4 w0 = *(const float4*)&Bw[ee*128+tx*8];
      float4 w1 = *(const float4*)&Bw[ee*128+tx*8+4];
      float4 v0 = *(const float4*)&B2[ee*128+tx*8];
      float4 v1 = *(const float4*)&B2[ee*128+tx*8+4];
      float bw[8]={w0.x,w0.y,w0.z,w0.w,w1.x,w1.y,w1.z,w1.w};
      float b2[8]={v0.x,v0.y,v0.z,v0.w,v1.x,v1.y,v1.z,v1.w};
      #pragma unroll
      for (int i=0;i<4;++i)
        #pragma unroll
        for (int j=0;j<8;++j){
          accM[i][j] = fmaf(am[i],  bw[j], accM[i][j]);
          accS[i][j] = fmaf(as_[i], b2[j], accS[i][j]);
        }
    }
  }
  float rc[4];
  #pragma unroll
  for (int i=0;i<4;++i) rc[i] = rcomb[r0+ty*4+i];
  float ws[8];
  #pragma unroll
  for (int j=0;j<8;++j) ws[j] = wso[c0+tx*8+j];
  #pragma unroll
  for (int i=0;i<4;++i){
    long basei = (long)(r0+ty*4+i)*EN + c0 + tx*8;
    float mo[8], so[8];
    #pragma unroll
    for (int j=0;j<8;++j){
      mo[j] = accM[i][j];
      float spre = accS[i][j] + rc[i]*ws[j];     // S1 + S2 + S3
      so[j] = sp_f(sp_f(spre));                  // double softplus
    }
    float4 m0={mo[0],mo[1],mo[2],mo[3]}, m1={mo[4],mo[5],mo[6],mo[7]};
    float4 s0={so[0],so[1],so[2],so[3]}, s1={so[4],so[5],so[6],so[7]};
    *(float4*)&mu_out[basei]   = m0; *(float4*)&mu_out[basei+4]   = m1;
    *(float4*)&sg_out[basei]   = s0; *(float4*)&sg_out[basei+4]   = s1;
  }
}

// ---- KL finalize ----
__global__ void k_klf(const float* __restrict__ klacc, float* __restrict__ out){
  // kl = sum_l 0.5*( ln(0.01)-1 - mean(sig) + mean(sp(sig))/0.01 + mean(mu^2)/0.01 )
  float Smu2 = klacc[0], Ssig = klacc[1], Ssp = klacc[2];
  const float C = -5.60517018599f;   // ln(0.01) - 1
  out[0] = 0.5f*(4.f*C - Ssig*(1.0f/768.0f) + Ssp*(1.0f/7.68f) + Smu2*(1.0f/5898.24f));
}

extern "C" void kernel_launch(void* const* d_in, const int* in_sizes, int n_in,
                              void* d_out, int out_size, void* d_ws, size_t ws_size,
                              hipStream_t stream) {
  (void)in_sizes; (void)n_in; (void)out_size;
  const float* x       = (const float*)d_in[0];
  const float* wq_mu   = (const float*)d_in[1];
  const float* wq_sig  = (const float*)d_in[2];
  const float* wk_mu   = (const float*)d_in[3];
  const float* wk_sig  = (const float*)d_in[4];
  const float* wv_mu   = (const float*)d_in[5];
  const float* wv_sig  = (const float*)d_in[6];
  const float* wo_mu   = (const float*)d_in[7];
  const float* wo_sig  = (const float*)d_in[8];

  float* ws   = (float*)d_ws;        // requires ws_size >= 63 MB
  float* mq   = ws + OFF_MQ;
  float* mk   = ws + OFF_MK;
  float* mv   = ws + OFF_MV;
  float* muc  = ws + OFF_MUC;
  float* sgc  = ws + OFF_SGC;
  float* xx   = ws + OFF_XX;
  float* rc   = ws + OFF_RC;
  float* wsig = ws + OFF_WS;
  float* kla  = ws + OFF_KL;

  float* mu_out = (float*)d_out;
  float* sg_out = mu_out + BSE;
  float* kl_out = mu_out + 2*BSE;

  (void)hipMemsetAsync(kla, 0, 3*sizeof(float), stream);
  k_prep<<<4, 256, 0, stream>>>(wq_sig, wk_sig, wv_sig, wo_sig, wsig, kla);
  k_xx<<<BSN, 256, 0, stream>>>(x, xx);
  k_mu2<<<dim3(64,4), 256, 0, stream>>>(wq_mu, wk_mu, wv_mu, wo_mu, kla);
  k_proj<<<dim3(6,64,3), 256, 0, stream>>>(x, wq_mu, wk_mu, wv_mu, mq, mk, mv);

  const int attn_lds = 29376*4;
  (void)hipFuncSetAttribute((const void*)k_attn,
                      hipFuncAttributeMaxDynamicSharedMemorySize, attn_lds);
  k_attn<<<dim3(16,HN,BN), 256, attn_lds, stream>>>(mq, mk, mv, xx, wsig, muc, sgc);

  k_rows<<<BSN, 256, 0, stream>>>(muc, sgc, rc);
  k_out<<<dim3(6,64), 256, 0, stream>>>(muc, sgc, wo_mu, rc, wsig + 3*EN, mu_out, sg_out);
  k_klf<<<1, 1, 0, stream>>>(kla, kl_out);
}

// Round 3
// 463.952 us; speedup vs baseline: 5.2137x; 5.2137x over previous
//
#include <hip/hip_runtime.h>
#include <math.h>

#define EN 768
#define SN 1024
#define HN 12
#define BSN 4096
#define BSE 3145728

typedef __attribute__((ext_vector_type(8))) short bf16x8;
typedef __attribute__((ext_vector_type(4))) float f32x4;
typedef unsigned short u16;

// ---- workspace byte offsets (total ~58.6 MB) ----
#define OFF_XX   0u
#define OFF_RC   16384u
#define OFF_WSIG 32768u      // [4][768] f32
#define OFF_KL   45056u      // [3] f32
#define OFF_WT   65536u      // 4 * 768*768 ushort (q,k,v,o transposed bf16)
#define OFF_QH   4784128u    // each big array: 4096*768 ushort = 6291456 B
#define OFF_KH   11075584u
#define OFF_VH   17367040u
#define OFF_SQD  23658496u
#define OFF_SKD  29949952u
#define OFF_MUH  36241408u
#define OFF_SGH  42532864u
#define OFF_MVT  48824320u
#define OFF_SVT  55115776u

__device__ __forceinline__ float sp_f(float x){
  return fmaxf(x, 0.f) + log1pf(__expf(-fabsf(x)));
}
__device__ __forceinline__ u16 f2b(float f){
  unsigned u = __float_as_uint(f);
  return (u16)((u + 0x7fffu + ((u>>16)&1u)) >> 16);
}
__device__ __forceinline__ float b2f(u16 h){
  return __uint_as_float(((unsigned)h)<<16);
}
__device__ __forceinline__ f32x4 mfma16(bf16x8 a, bf16x8 b, f32x4 c){
  return __builtin_amdgcn_mfma_f32_16x16x32_bf16(a, b, c, 0, 0, 0);
}
// square a bf16x8 elementwise -> bf16x8
__device__ __forceinline__ bf16x8 sq8(bf16x8 a){
  bf16x8 r;
  #pragma unroll
  for (int i=0;i<8;++i){ float f = b2f((u16)a[i]); r[i] = (short)f2b(f*f); }
  return r;
}
// LDS frag read: tile [rows][64] bf16, XOR-swizzled; sg = kstep*4 + (lane>>4)
__device__ __forceinline__ bf16x8 ldsr(const u16* t, int row, int sg){
  int a16 = (row<<3) + (sg ^ (row&7));
  return *(const bf16x8*)(t + (a16<<3));
}
// stage a 64x64 bf16 tile (row stride rstride elems) into swizzled LDS
__device__ __forceinline__ void stage64(u16* dst, const u16* src, int rstride, int tid){
  #pragma unroll
  for (int it=0; it<2; ++it){
    int idx = (it<<8) + tid;
    int row = idx>>3, seg = idx&7;
    bf16x8 v = *(const bf16x8*)(src + (long)row*rstride + (seg<<3));
    int a16 = (row<<3) + (seg ^ (row&7));
    *(bf16x8*)(dst + (a16<<3)) = v;
  }
}

__device__ __forceinline__ float blk_reduce(float v, float* tmp){
  #pragma unroll
  for (int off = 32; off; off >>= 1) v += __shfl_down(v, off, 64);
  int w = threadIdx.x >> 6;
  if ((threadIdx.x & 63) == 0) tmp[w] = v;
  __syncthreads();
  float r = 0.f;
  if (threadIdx.x == 0) r = tmp[0] + tmp[1] + tmp[2] + tmp[3];
  __syncthreads();
  return r;
}

// ---- softplus(w_sigma) vectors + KL sigma terms ----
__global__ void k_prep(const float* __restrict__ s0, const float* __restrict__ s1,
                       const float* __restrict__ s2, const float* __restrict__ s3,
                       float* __restrict__ wsig, float* __restrict__ klacc){
  __shared__ float tmp[4];
  const float* src = (blockIdx.x==0)?s0:(blockIdx.x==1)?s1:(blockIdx.x==2)?s2:s3;
  int l = blockIdx.x;
  float ssum=0.f, spsum=0.f;
  for (int j=threadIdx.x; j<EN; j+=256){
    float sg = src[j];
    float w  = log1pf(__expf(sg));
    wsig[l*EN+j] = w;
    ssum += sg; spsum += w;
  }
  float a = blk_reduce(ssum, tmp);
  float b = blk_reduce(spsum, tmp);
  if (threadIdx.x==0){ atomicAdd(&klacc[1], a); atomicAdd(&klacc[2], b); }
}

// ---- xx[r] = sum_e (x/768)^2 ----
__global__ void k_xx(const float* __restrict__ x, float* __restrict__ xx){
  __shared__ float tmp[4];
  int r = blockIdx.x;
  const float* xr = x + (long)r*EN;
  float s=0.f;
  for (int j=threadIdx.x; j<EN; j+=256){ float v = xr[j]; s += v*v; }
  float t = blk_reduce(s, tmp);
  if (threadIdx.x==0) xx[r] = t*(1.0f/589824.0f);
}

// ---- sum mu^2 over the four weight matrices (KL) ----
__global__ void k_mu2(const float* __restrict__ w0, const float* __restrict__ w1,
                      const float* __restrict__ w2, const float* __restrict__ w3,
                      float* __restrict__ klacc){
  __shared__ float tmp[4];
  const float* w = (blockIdx.y==0)?w0:(blockIdx.y==1)?w1:(blockIdx.y==2)?w2:w3;
  const float4* w4 = (const float4*)w;
  float s=0.f;
  for (int i=blockIdx.x*256+threadIdx.x; i<147456; i+=gridDim.x*256){
    float4 v = w4[i];
    s += v.x*v.x + v.y*v.y + v.z*v.z + v.w*v.w;
  }
  float r = blk_reduce(s, tmp);
  if (threadIdx.x==0) atomicAdd(&klacc[0], r);
}

// ---- transpose weights to bf16: WT[l][c][r] = bf16(W_l[r][c]) ----
__global__ void k_wt(const float* __restrict__ w0, const float* __restrict__ w1,
                     const float* __restrict__ w2, const float* __restrict__ w3,
                     u16* __restrict__ wt){
  __shared__ float t[64*65];
  const float* W = (blockIdx.z==0)?w0:(blockIdx.z==1)?w1:(blockIdx.z==2)?w2:w3;
  u16* WT = wt + (long)blockIdx.z*589824;
  int r0 = blockIdx.y<<6, c0 = blockIdx.x<<6;
  int tid = threadIdx.x;
  #pragma unroll
  for (int it=0; it<16; ++it){
    int idx=(it<<8)+tid; int r=idx>>6, c=idx&63;
    t[c*65+r] = W[(long)(r0+r)*EN + c0+c];
  }
  __syncthreads();
  #pragma unroll
  for (int it=0; it<16; ++it){
    int idx=(it<<8)+tid; int c=idx>>6, r=idx&63;
    WT[(long)(c0+c)*EN + r0+r] = f2b(t[c*65+r]);
  }
}

// ---- sq/64, sk/64 arrays (bf16) ----
__global__ void k_sigarr(const float* __restrict__ xx, const float* __restrict__ wsig,
                         u16* __restrict__ sqd, u16* __restrict__ skd){
  int r = blockIdx.x;
  float xr = xx[r];
  for (int c=threadIdx.x; c<EN; c+=256){
    sqd[(long)r*EN+c] = f2b(sp_f(xr*wsig[c])*(1.0f/64.0f));
    skd[(long)r*EN+c] = f2b(sp_f(xr*wsig[EN+c])*(1.0f/64.0f));
  }
}

// ---- projection GEMM: out = bf16(x @ W) via MFMA; z selects q/k/v ----
__global__ __launch_bounds__(256)
void k_projmm(const float* __restrict__ x, const u16* __restrict__ WT,
              u16* __restrict__ oq, u16* __restrict__ ok, u16* __restrict__ ov){
  __shared__ __align__(16) u16 lds[8192];      // A 8KB + B 8KB
  u16* At = lds; u16* Bt = lds + 4096;
  const int tid = threadIdx.x;
  const int w = tid>>6, l = tid&63, l15 = l&15, g = l>>4;
  const int m0 = blockIdx.y<<6, n0 = blockIdx.x<<6;
  const u16* Wt = WT + (long)blockIdx.z*589824;
  u16* out = (blockIdx.z==0)?oq:(blockIdx.z==1)?ok:ov;
  f32x4 acc[4];
  #pragma unroll
  for (int t=0;t<4;++t){ acc[t][0]=0;acc[t][1]=0;acc[t][2]=0;acc[t][3]=0; }
  for (int k0=0; k0<EN; k0+=64){
    __syncthreads();
    #pragma unroll
    for (int it=0; it<2; ++it){               // stage A from f32 x -> bf16
      int idx=(it<<8)+tid; int row=idx>>3, seg=idx&7;
      const float* sp = x + (long)(m0+row)*EN + k0 + (seg<<3);
      float4 a = *(const float4*)sp; float4 c = *(const float4*)(sp+4);
      bf16x8 v;
      v[0]=(short)f2b(a.x); v[1]=(short)f2b(a.y); v[2]=(short)f2b(a.z); v[3]=(short)f2b(a.w);
      v[4]=(short)f2b(c.x); v[5]=(short)f2b(c.y); v[6]=(short)f2b(c.z); v[7]=(short)f2b(c.w);
      int a16=(row<<3)+(seg^(row&7));
      *(bf16x8*)(At + (a16<<3)) = v;
    }
    stage64(Bt, Wt + (long)n0*EN + k0, EN, tid);
    __syncthreads();
    #pragma unroll
    for (int s=0;s<2;++s){
      int sg=(s<<2)+g;
      bf16x8 af = ldsr(At, (w<<4)+l15, sg);
      #pragma unroll
      for (int t=0;t<4;++t)
        acc[t] = mfma16(af, ldsr(Bt,(t<<4)+l15,sg), acc[t]);
    }
  }
  #pragma unroll
  for (int t=0;t<4;++t){
    int col = n0 + (t<<4) + l15;
    #pragma unroll
    for (int r=0;r<4;++r){
      long row = m0 + (w<<4) + (g<<2) + r;
      out[row*EN + col] = f2b(acc[t][r]);
    }
  }
}

// ---- per-(b,h): transpose vh slice -> mvT, and build svT directly transposed ----
__global__ void k_vt(const u16* __restrict__ vh, const float* __restrict__ xx,
                     const float* __restrict__ wsig, u16* __restrict__ mvT,
                     u16* __restrict__ svT){
  __shared__ u16 t[64*65];
  int kt = blockIdx.x, h = blockIdx.y, b = blockIdx.z;
  long tok0 = (long)b*SN + (kt<<6);
  int tid = threadIdx.x;
  #pragma unroll
  for (int it=0; it<16; ++it){
    int idx=(it<<8)+tid; int r=idx>>6, c=idx&63;     // r=token, c=d
    t[c*65+r] = vh[(tok0+r)*EN + (h<<6) + c];
  }
  __syncthreads();
  long obase = ((long)(b*HN+h)<<6)*SN + (kt<<6);
  #pragma unroll
  for (int it=0; it<16; ++it){
    int idx=(it<<8)+tid; int d=idx>>6, k=idx&63;
    mvT[obase + (long)d*SN + k] = t[d*65+k];
    float sv = sp_f(xx[(long)b*SN + (kt<<6) + k] * wsig[2*EN + (h<<6) + d]);
    svT[obase + (long)d*SN + k] = f2b(sv);
  }
}

// ---- fused Bayesian attention, MFMA, per (q-tile64, h, b); 40KB LDS ----
__global__ __launch_bounds__(256)
void k_attn(const u16* __restrict__ qh, const u16* __restrict__ kh,
            const u16* __restrict__ sqd, const u16* __restrict__ skd,
            const u16* __restrict__ mvT, const u16* __restrict__ svT,
            u16* __restrict__ muh, u16* __restrict__ sgh){
  __shared__ __align__(16) u16 lds[20480];
  u16* T0 = lds; u16* T1 = lds + 4096; u16* T2 = lds + 8192;
  const int tid = threadIdx.x;
  const int w = tid>>6, l = tid&63, l15 = l&15, g = l>>4;
  u16* Pw = lds + 12288 + w*2048;
  u16* Pg = Pw + 1024;
  const int q0 = blockIdx.x<<6, h = blockIdx.y, b = blockIdx.z;
  const long bS = (long)b*SN;

  // A-fragments in registers (constant across all k-tiles)
  bf16x8 amq[2], acb[2], amk2[2];
  {
    long qrow = (bS + q0 + (w<<4) + l15) * EN;
    #pragma unroll
    for (int s=0;s<2;++s){
      int eoff = (h<<6) + (s<<5) + (g<<3);
      bf16x8 q8 = *(const bf16x8*)(qh + qrow + eoff);
      bf16x8 k8 = *(const bf16x8*)(kh + qrow + eoff);
      bf16x8 s8 = *(const bf16x8*)(sqd + qrow + eoff);
      amq[s] = q8;
      bf16x8 t2, tc;
      #pragma unroll
      for (int j=0;j<8;++j){
        float kv = b2f((u16)k8[j]);
        t2[j] = (short)f2b(kv*kv);                          // mk_q^2
        float qv = b2f((u16)q8[j]);
        float sv = b2f((u16)s8[j]) * 64.0f;                 // sq
        tc[j] = (short)f2b(qv*qv + sv);                     // mq^2 + sq
      }
      amk2[s] = t2; acb[s] = tc;
    }
  }

  const u16* khb = kh + bS*EN + (h<<6);
  const u16* sqb = sqd + bS*EN + (h<<6);
  const u16* skb = skd + bS*EN + (h<<6);
  const u16* mvb = mvT + ((long)(b*HN+h)<<6)*SN;
  const u16* svb = svT + ((long)(b*HN+h)<<6)*SN;

  // ---- pass 1: Z ----
  f32x4 zacc = {0.f,0.f,0.f,0.f};
  for (int kt=0; kt<16; ++kt){
    __syncthreads();
    stage64(T0, khb + (long)(kt<<6)*EN, EN, tid);
    __syncthreads();
    f32x4 smu[4];
    #pragma unroll
    for (int t=0;t<4;++t){ smu[t][0]=0;smu[t][1]=0;smu[t][2]=0;smu[t][3]=0; }
    #pragma unroll
    for (int s=0;s<2;++s){
      int sg=(s<<2)+g;
      #pragma unroll
      for (int t=0;t<4;++t)
        smu[t] = mfma16(amq[s], ldsr(T0,(t<<4)+l15,sg), smu[t]);
    }
    #pragma unroll
    for (int t=0;t<4;++t)
      #pragma unroll
      for (int r=0;r<4;++r)
        zacc[r] += __expf(smu[t][r]*0.125f);
  }
  #pragma unroll
  for (int m=1; m<16; m<<=1){
    #pragma unroll
    for (int r=0;r<4;++r) zacc[r] += __shfl_xor(zacc[r], m, 64);
  }
  f32x4 zinv;
  #pragma unroll
  for (int r=0;r<4;++r) zinv[r] = 1.0f/zacc[r];

  // ---- pass 2 ----
  f32x4 accM[4], acc2[4], acc3[4];
  #pragma unroll
  for (int t=0;t<4;++t){
    accM[t][0]=0;accM[t][1]=0;accM[t][2]=0;accM[t][3]=0;
    acc2[t][0]=0;acc2[t][1]=0;acc2[t][2]=0;acc2[t][3]=0;
    acc3[t][0]=0;acc3[t][1]=0;acc3[t][2]=0;acc3[t][3]=0;
  }
  for (int kt=0; kt<16; ++kt){
    __syncthreads();
    stage64(T0, khb + (long)(kt<<6)*EN, EN, tid);
    stage64(T1, skb + (long)(kt<<6)*EN, EN, tid);
    stage64(T2, sqb + (long)(kt<<6)*EN, EN, tid);
    __syncthreads();
    f32x4 smu[4], ssg[4];
    #pragma unroll
    for (int t=0;t<4;++t){
      smu[t][0]=0;smu[t][1]=0;smu[t][2]=0;smu[t][3]=0;
      ssg[t][0]=0;ssg[t][1]=0;ssg[t][2]=0;ssg[t][3]=0;
    }
    #pragma unroll
    for (int s=0;s<2;++s){
      int sg=(s<<2)+g;
      #pragma unroll
      for (int t=0;t<4;++t){
        int rn = (t<<4)+l15;
        smu[t] = mfma16(amq[s],  ldsr(T0,rn,sg), smu[t]);
        ssg[t] = mfma16(acb[s],  ldsr(T1,rn,sg), ssg[t]);   // a + c terms
        ssg[t] = mfma16(amk2[s], ldsr(T2,rn,sg), ssg[t]);   // b term
      }
    }
    // S -> P (w, Sw) into per-wave LDS tiles
    #pragma unroll
    for (int t=0;t<4;++t){
      #pragma unroll
      for (int r=0;r<4;++r){
        float e  = __expf(smu[t][r]*0.125f);
        float wv = e*zinv[r];
        float u  = wv - wv*wv;
        float sw = u*u*ssg[t][r]*(1.0f/65536.0f);
        int row = (g<<2)+r, col = (t<<4)+l15;
        int off = (((row<<3) + ((col>>3) ^ (row&7)))<<3) + (col&7);
        Pw[off] = f2b(wv);
        Pg[off] = f2b(sw);
      }
    }
    __syncthreads();
    stage64(T0, mvb + (kt<<6), SN, tid);
    stage64(T1, svb + (kt<<6), SN, tid);
    __syncthreads();
    #pragma unroll
    for (int s=0;s<2;++s){
      int sg=(s<<2)+g;
      bf16x8 aw = ldsr(Pw, l15, sg);
      bf16x8 ag = ldsr(Pg, l15, sg);
      bf16x8 pa;                                       // w^2 + Sw
      #pragma unroll
      for (int j=0;j<8;++j){
        float wf = b2f((u16)aw[j]);
        pa[j] = (short)f2b(wf*wf + b2f((u16)ag[j]));
      }
      #pragma unroll
      for (int t=0;t<4;++t){
        int rn = (t<<4)+l15;
        bf16x8 bm = ldsr(T0,rn,sg);
        accM[t] = mfma16(aw, bm, accM[t]);
        acc2[t] = mfma16(pa, ldsr(T1,rn,sg), acc2[t]);
        acc3[t] = mfma16(ag, sq8(bm), acc3[t]);
      }
    }
  }
  // epilogue
  long grow0 = bS + q0 + (w<<4) + (g<<2);
  #pragma unroll
  for (int t=0;t<4;++t){
    int col = (h<<6) + (t<<4) + l15;
    #pragma unroll
    for (int r=0;r<4;++r){
      long o = (grow0 + r)*EN + col;
      muh[o] = f2b(accM[t][r]);
      sgh[o] = f2b(sp_f((acc2[t][r]+acc3[t][r])*(1.0f/1024.0f)));
    }
  }
}

// ---- per-row combined scalar for S2+S3 ----
__global__ void k_rows(const u16* __restrict__ muh, const u16* __restrict__ sgh,
                       float* __restrict__ rcomb){
  __shared__ float tmp[4];
  int r = blockIdx.x;
  const u16* m = muh + (long)r*EN;
  const u16* s = sgh + (long)r*EN;
  float s1=0.f, s2=0.f;
  for (int j=threadIdx.x; j<EN; j+=256){ float a=b2f(m[j]); s1+=a*a; s2+=b2f(s[j]); }
  float r1 = blk_reduce(s1, tmp);
  float r2 = blk_reduce(s2, tmp);
  if (threadIdx.x==0) rcomb[r] = r1*(1.0f/589824.0f) + r2*(1.0f/768.0f);
}

// ---- output linear (MFMA) with fused Sigma epilogue ----
__global__ __launch_bounds__(256)
void k_outmm(const u16* __restrict__ muh, const u16* __restrict__ sgh,
             const u16* __restrict__ WTo, const float* __restrict__ rcomb,
             const float* __restrict__ wso, float* __restrict__ mu_out,
             float* __restrict__ sg_out){
  __shared__ __align__(16) u16 lds[12288];
  u16* Am = lds; u16* As = lds + 4096; u16* Bt = lds + 8192;
  const int tid = threadIdx.x;
  const int w = tid>>6, l = tid&63, l15 = l&15, g = l>>4;
  const int m0 = blockIdx.y<<6, n0 = blockIdx.x<<6;
  f32x4 accM[4], accS[4];
  #pragma unroll
  for (int t=0;t<4;++t){
    accM[t][0]=0;accM[t][1]=0;accM[t][2]=0;accM[t][3]=0;
    accS[t][0]=0;accS[t][1]=0;accS[t][2]=0;accS[t][3]=0;
  }
  for (int k0=0; k0<EN; k0+=64){
    __syncthreads();
    stage64(Am, muh + (long)m0*EN + k0, EN, tid);
    stage64(As, sgh + (long)m0*EN + k0, EN, tid);
    stage64(Bt, WTo + (long)n0*EN + k0, EN, tid);
    __syncthreads();
    #pragma unroll
    for (int s=0;s<2;++s){
      int sg=(s<<2)+g;
      bf16x8 am = ldsr(Am, (w<<4)+l15, sg);
      bf16x8 as = ldsr(As, (w<<4)+l15, sg);
      #pragma unroll
      for (int t=0;t<4;++t){
        bf16x8 bw = ldsr(Bt,(t<<4)+l15,sg);
        accM[t] = mfma16(am, bw, accM[t]);
        accS[t] = mfma16(as, sq8(bw), accS[t]);      // (wo^2); /768 in epilogue
      }
    }
  }
  float rc4[4];
  #pragma unroll
  for (int r=0;r<4;++r) rc4[r] = rcomb[m0 + (w<<4) + (g<<2) + r];
  #pragma unroll
  for (int t=0;t<4;++t){
    int col = n0 + (t<<4) + l15;
    float wsc = wso[col];
    #pragma unroll
    for (int r=0;r<4;++r){
      long row = m0 + (w<<4) + (g<<2) + r;
      mu_out[row*EN + col] = accM[t][r];
      float spre = accS[t][r]*(1.0f/768.0f) + rc4[r]*wsc;   // S1+S2+S3
      sg_out[row*EN + col] = sp_f(sp_f(spre));
    }
  }
}

// ---- KL finalize ----
__global__ void k_klf(const float* __restrict__ klacc, float* __restrict__ out){
  float Smu2 = klacc[0], Ssig = klacc[1], Ssp = klacc[2];
  const float C = -5.60517018599f;   // ln(0.01) - 1
  out[0] = 0.5f*(4.f*C - Ssig*(1.0f/768.0f) + Ssp*(1.0f/7.68f) + Smu2*(1.0f/5898.24f));
}

extern "C" void kernel_launch(void* const* d_in, const int* in_sizes, int n_in,
                              void* d_out, int out_size, void* d_ws, size_t ws_size,
                              hipStream_t stream) {
  (void)in_sizes; (void)n_in; (void)out_size; (void)ws_size;
  const float* x      = (const float*)d_in[0];
  const float* wq_mu  = (const float*)d_in[1];
  const float* wq_sig = (const float*)d_in[2];
  const float* wk_mu  = (const float*)d_in[3];
  const float* wk_sig = (const float*)d_in[4];
  const float* wv_mu  = (const float*)d_in[5];
  const float* wv_sig = (const float*)d_in[6];
  const float* wo_mu  = (const float*)d_in[7];
  const float* wo_sig = (const float*)d_in[8];

  char* wsb = (char*)d_ws;
  float* xx    = (float*)(wsb + OFF_XX);
  float* rc    = (float*)(wsb + OFF_RC);
  float* wsig  = (float*)(wsb + OFF_WSIG);
  float* kla   = (float*)(wsb + OFF_KL);
  u16*   WT    = (u16*)(wsb + OFF_WT);
  u16*   qh    = (u16*)(wsb + OFF_QH);
  u16*   kh    = (u16*)(wsb + OFF_KH);
  u16*   vh    = (u16*)(wsb + OFF_VH);
  u16*   sqd   = (u16*)(wsb + OFF_SQD);
  u16*   skd   = (u16*)(wsb + OFF_SKD);
  u16*   muh   = (u16*)(wsb + OFF_MUH);
  u16*   sgh   = (u16*)(wsb + OFF_SGH);
  u16*   mvT   = (u16*)(wsb + OFF_MVT);
  u16*   svT   = (u16*)(wsb + OFF_SVT);

  float* mu_out = (float*)d_out;
  float* sg_out = mu_out + BSE;
  float* kl_out = mu_out + 2*BSE;

  (void)hipMemsetAsync(kla, 0, 3*sizeof(float), stream);
  k_prep<<<4, 256, 0, stream>>>(wq_sig, wk_sig, wv_sig, wo_sig, wsig, kla);
  k_xx<<<BSN, 256, 0, stream>>>(x, xx);
  k_mu2<<<dim3(64,4), 256, 0, stream>>>(wq_mu, wk_mu, wv_mu, wo_mu, kla);
  k_wt<<<dim3(12,12,4), 256, 0, stream>>>(wq_mu, wk_mu, wv_mu, wo_mu, WT);
  k_sigarr<<<BSN, 256, 0, stream>>>(xx, wsig, sqd, skd);
  k_projmm<<<dim3(12,64,3), 256, 0, stream>>>(x, WT, qh, kh, vh);
  k_vt<<<dim3(16,HN,4), 256, 0, stream>>>(vh, xx, wsig, mvT, svT);
  k_attn<<<dim3(16,HN,4), 256, 0, stream>>>(qh, kh, sqd, skd, mvT, svT, muh, sgh);
  k_rows<<<BSN, 256, 0, stream>>>(muh, sgh, rc);
  k_outmm<<<dim3(12,64), 256, 0, stream>>>(muh, sgh, WT + 3l*589824, rc,
                                           wsig + 3*EN, mu_out, sg_out);
  k_klf<<<1, 1, 0, stream>>>(kla, kl_out);
}

// Round 4
// 437.077 us; speedup vs baseline: 5.5343x; 1.0615x over previous
//
#include <hip/hip_runtime.h>
#include <math.h>

#define EN 768
#define SN 1024
#define HN 12
#define BSN 4096
#define BSE 3145728

typedef __attribute__((ext_vector_type(8))) short bf16x8;
typedef __attribute__((ext_vector_type(4))) float f32x4;
typedef __attribute__((ext_vector_type(4))) unsigned short u16x4;
typedef unsigned short u16;

// ---- workspace byte offsets (~58.8 MB) ----
#define OFF_XX   0u
#define OFF_RC   16384u
#define OFF_WSIG 32768u
#define OFF_KL   45056u
#define OFF_ZI   49152u       // [4*12*1024] f32 zinv
#define OFF_WT   262144u      // 4 * 768*768 u16
#define OFF_QH   4980736u
#define OFF_KH   11272192u
#define OFF_SQD  17563648u
#define OFF_SKD  23855104u
#define OFF_MVT  30146560u
#define OFF_MV2  36438016u
#define OFF_SVT  42729472u
#define OFF_MUH  49020928u
#define OFF_SGH  55312384u

__device__ __forceinline__ float sp_f(float x){
  return fmaxf(x, 0.f) + log1pf(__expf(-fabsf(x)));
}
__device__ __forceinline__ u16 f2b(float f){
  unsigned u = __float_as_uint(f);
  return (u16)((u + 0x7fffu + ((u>>16)&1u)) >> 16);
}
__device__ __forceinline__ float b2f(u16 h){
  return __uint_as_float(((unsigned)h)<<16);
}
__device__ __forceinline__ f32x4 mfma16(bf16x8 a, bf16x8 b, f32x4 c){
  return __builtin_amdgcn_mfma_f32_16x16x32_bf16(a, b, c, 0, 0, 0);
}
// LDS frag read from swizzled [rows][64] bf16 tile
__device__ __forceinline__ bf16x8 ldsr(const u16* t, int row, int sg){
  int a16 = (row<<3) + (sg ^ (row&7));
  return *(const bf16x8*)(t + (a16<<3));
}
// stage 64x64 bf16 tile with 256 threads (2 slots/thread)
__device__ __forceinline__ void stage64(u16* dst, const u16* src, int rstride, int tid){
  #pragma unroll
  for (int it=0; it<2; ++it){
    int idx = (it<<8) + tid;
    int row = idx>>3, seg = idx&7;
    bf16x8 v = *(const bf16x8*)(src + (long)row*rstride + (seg<<3));
    int a16 = (row<<3) + (seg ^ (row&7));
    *(bf16x8*)(dst + (a16<<3)) = v;
  }
}

__device__ __forceinline__ float blk_reduce(float v, float* tmp){
  #pragma unroll
  for (int off = 32; off; off >>= 1) v += __shfl_down(v, off, 64);
  int w = threadIdx.x >> 6;
  if ((threadIdx.x & 63) == 0) tmp[w] = v;
  __syncthreads();
  float r = 0.f;
  if (threadIdx.x == 0) r = tmp[0] + tmp[1] + tmp[2] + tmp[3];
  __syncthreads();
  return r;
}

// ---- softplus(w_sigma) + KL sigma terms ----
__global__ void k_prep(const float* __restrict__ s0, const float* __restrict__ s1,
                       const float* __restrict__ s2, const float* __restrict__ s3,
                       float* __restrict__ wsig, float* __restrict__ klacc){
  __shared__ float tmp[4];
  const float* src = (blockIdx.x==0)?s0:(blockIdx.x==1)?s1:(blockIdx.x==2)?s2:s3;
  int l = blockIdx.x;
  float ssum=0.f, spsum=0.f;
  for (int j=threadIdx.x; j<EN; j+=256){
    float sg = src[j];
    float w  = log1pf(__expf(sg));
    wsig[l*EN+j] = w;
    ssum += sg; spsum += w;
  }
  float a = blk_reduce(ssum, tmp);
  float b = blk_reduce(spsum, tmp);
  if (threadIdx.x==0){ atomicAdd(&klacc[1], a); atomicAdd(&klacc[2], b); }
}

// ---- xx[r] = sum_e (x/768)^2 ----
__global__ void k_xx(const float* __restrict__ x, float* __restrict__ xx){
  __shared__ float tmp[4];
  int r = blockIdx.x;
  const float* xr = x + (long)r*EN;
  float s=0.f;
  for (int j=threadIdx.x; j<EN; j+=256){ float v = xr[j]; s += v*v; }
  float t = blk_reduce(s, tmp);
  if (threadIdx.x==0) xx[r] = t*(1.0f/589824.0f);
}

// ---- KL mu^2 ----
__global__ void k_mu2(const float* __restrict__ w0, const float* __restrict__ w1,
                      const float* __restrict__ w2, const float* __restrict__ w3,
                      float* __restrict__ klacc){
  __shared__ float tmp[4];
  const float* w = (blockIdx.y==0)?w0:(blockIdx.y==1)?w1:(blockIdx.y==2)?w2:w3;
  const float4* w4 = (const float4*)w;
  float s=0.f;
  for (int i=blockIdx.x*256+threadIdx.x; i<147456; i+=gridDim.x*256){
    float4 v = w4[i];
    s += v.x*v.x + v.y*v.y + v.z*v.z + v.w*v.w;
  }
  float r = blk_reduce(s, tmp);
  if (threadIdx.x==0) atomicAdd(&klacc[0], r);
}

// ---- transpose weights to bf16 ----
__global__ void k_wt(const float* __restrict__ w0, const float* __restrict__ w1,
                     const float* __restrict__ w2, const float* __restrict__ w3,
                     u16* __restrict__ wt){
  __shared__ float t[64*65];
  const float* W = (blockIdx.z==0)?w0:(blockIdx.z==1)?w1:(blockIdx.z==2)?w2:w3;
  u16* WT = wt + (long)blockIdx.z*589824;
  int r0 = blockIdx.y<<6, c0 = blockIdx.x<<6;
  int tid = threadIdx.x;
  #pragma unroll
  for (int it=0; it<16; ++it){
    int idx=(it<<8)+tid; int r=idx>>6, c=idx&63;
    t[c*65+r] = W[(long)(r0+r)*EN + c0+c];
  }
  __syncthreads();
  #pragma unroll
  for (int it=0; it<16; ++it){
    int idx=(it<<8)+tid; int c=idx>>6, r=idx&63;
    WT[(long)(c0+c)*EN + r0+r] = f2b(t[c*65+r]);
  }
}

// ---- sq/64, sk/64 arrays ----
__global__ void k_sigarr(const float* __restrict__ xx, const float* __restrict__ wsig,
                         u16* __restrict__ sqd, u16* __restrict__ skd){
  int r = blockIdx.x;
  float xr = xx[r];
  for (int c=threadIdx.x; c<EN; c+=256){
    sqd[(long)r*EN+c] = f2b(sp_f(xr*wsig[c])*(1.0f/64.0f));
    skd[(long)r*EN+c] = f2b(sp_f(xr*wsig[EN+c])*(1.0f/64.0f));
  }
}

// ---- svT[b,h][d][k] = softplus(xx[b,k]*wsig_v[h,d]) ----
__global__ void k_svt(const float* __restrict__ xx, const float* __restrict__ wsig,
                      u16* __restrict__ svT){
  __shared__ float sxx[64], swv[64];
  int kt=blockIdx.x, h=blockIdx.y, b=blockIdx.z, tid=threadIdx.x;
  if (tid < 64){
    sxx[tid] = xx[(long)b*SN + (kt<<6) + tid];
    swv[tid] = wsig[2*EN + (h<<6) + tid];
  }
  __syncthreads();
  long obase = (((long)(b*HN+h))<<6)*SN + (kt<<6);
  #pragma unroll
  for (int it=0; it<16; ++it){
    int idx=(it<<8)+tid; int d=idx>>6, k=idx&63;
    svT[obase + (long)d*SN + k] = f2b(sp_f(sxx[k]*swv[d]));
  }
}

// ---- projections via MFMA; z=2 (v) writes transposed mvT + mv2T ----
__global__ __launch_bounds__(256)
void k_projmm(const float* __restrict__ x, const u16* __restrict__ WT,
              u16* __restrict__ oq, u16* __restrict__ ok,
              u16* __restrict__ mvT, u16* __restrict__ mv2T){
  __shared__ __align__(16) u16 lds[8192];
  u16* At = lds; u16* Bt = lds + 4096;
  const int tid = threadIdx.x;
  const int w = tid>>6, l = tid&63, l15 = l&15, g = l>>4;
  const int m0 = blockIdx.y<<6, n0 = blockIdx.x<<6;
  const u16* Wt = WT + (long)blockIdx.z*589824;
  f32x4 acc[4];
  #pragma unroll
  for (int t=0;t<4;++t){ acc[t][0]=0;acc[t][1]=0;acc[t][2]=0;acc[t][3]=0; }
  for (int k0=0; k0<EN; k0+=64){
    __syncthreads();
    #pragma unroll
    for (int it=0; it<2; ++it){
      int idx=(it<<8)+tid; int row=idx>>3, seg=idx&7;
      const float* sp = x + (long)(m0+row)*EN + k0 + (seg<<3);
      float4 a = *(const float4*)sp; float4 c = *(const float4*)(sp+4);
      bf16x8 v;
      v[0]=(short)f2b(a.x); v[1]=(short)f2b(a.y); v[2]=(short)f2b(a.z); v[3]=(short)f2b(a.w);
      v[4]=(short)f2b(c.x); v[5]=(short)f2b(c.y); v[6]=(short)f2b(c.z); v[7]=(short)f2b(c.w);
      int a16=(row<<3)+(seg^(row&7));
      *(bf16x8*)(At + (a16<<3)) = v;
    }
    stage64(Bt, Wt + (long)n0*EN + k0, EN, tid);
    __syncthreads();
    #pragma unroll
    for (int s=0;s<2;++s){
      int sg=(s<<2)+g;
      bf16x8 af = ldsr(At, (w<<4)+l15, sg);
      #pragma unroll
      for (int t=0;t<4;++t)
        acc[t] = mfma16(af, ldsr(Bt,(t<<4)+l15,sg), acc[t]);
    }
  }
  if (blockIdx.z < 2){
    u16* out = blockIdx.z ? ok : oq;
    #pragma unroll
    for (int t=0;t<4;++t){
      int col = n0 + (t<<4) + l15;
      #pragma unroll
      for (int r=0;r<4;++r){
        long row = m0 + (w<<4) + (g<<2) + r;
        out[row*EN + col] = f2b(acc[t][r]);
      }
    }
  } else {
    int b  = m0 >> 10;
    int hh = n0 >> 6;
    long obase = (((long)(b*HN+hh))<<6)*SN;
    int tok0 = (m0 & 1023) + (w<<4) + (g<<2);
    #pragma unroll
    for (int t=0;t<4;++t){
      int d = (t<<4) + l15;
      u16x4 m4, s4;
      #pragma unroll
      for (int r=0;r<4;++r){
        u16 mb = f2b(acc[t][r]);
        m4[r] = mb;
        float mf = b2f(mb);
        s4[r] = f2b(mf*mf);
      }
      *(u16x4*)&mvT[obase + (long)d*SN + tok0]  = m4;
      *(u16x4*)&mv2T[obase + (long)d*SN + tok0] = s4;
    }
  }
}

// ---- Z kernel: zinv[b,h,q] = 1 / sum_k exp(mu_score/8) ----
__global__ __launch_bounds__(256)
void k_z(const u16* __restrict__ qh, const u16* __restrict__ kh,
         float* __restrict__ zi){
  __shared__ __align__(16) u16 Tk[4096];
  const int tid = threadIdx.x;
  const int w = tid>>6, l = tid&63, l15 = l&15, g = l>>4;
  const int q0 = blockIdx.x<<6, h = blockIdx.y, b = blockIdx.z;
  const long bS = (long)b*SN;
  bf16x8 amq[2];
  {
    long qrow = (bS + q0 + (w<<4) + l15) * EN;
    #pragma unroll
    for (int s=0;s<2;++s)
      amq[s] = *(const bf16x8*)(qh + qrow + (h<<6) + (s<<5) + (g<<3));
  }
  const u16* khb = kh + bS*EN + (h<<6);
  f32x4 zacc = {0.f,0.f,0.f,0.f};
  for (int kt=0; kt<16; ++kt){
    __syncthreads();
    stage64(Tk, khb + (long)(kt<<6)*EN, EN, tid);
    __syncthreads();
    f32x4 smu[4];
    #pragma unroll
    for (int t=0;t<4;++t){ smu[t][0]=0;smu[t][1]=0;smu[t][2]=0;smu[t][3]=0; }
    #pragma unroll
    for (int s=0;s<2;++s){
      int sg=(s<<2)+g;
      #pragma unroll
      for (int t=0;t<4;++t)
        smu[t] = mfma16(amq[s], ldsr(Tk,(t<<4)+l15,sg), smu[t]);
    }
    #pragma unroll
    for (int t=0;t<4;++t)
      #pragma unroll
      for (int r=0;r<4;++r)
        zacc[r] += __expf(smu[t][r]*0.125f);
  }
  #pragma unroll
  for (int m=1; m<16; m<<=1){
    #pragma unroll
    for (int r=0;r<4;++r) zacc[r] += __shfl_xor(zacc[r], m, 64);
  }
  if (l15 == 0){
    long zbase = (((long)(b*HN+h))<<10) + q0 + (w<<4) + (g<<2);
    #pragma unroll
    for (int r=0;r<4;++r) zi[zbase + r] = 1.0f/zacc[r];
  }
}

// ---- single-pass fused Bayesian attention; 8 waves, q-tile 128, 80KB LDS ----
__global__ __launch_bounds__(512, 4)
void k_attn(const u16* __restrict__ qh, const u16* __restrict__ kh,
            const u16* __restrict__ sqd, const u16* __restrict__ skd,
            const u16* __restrict__ mvT, const u16* __restrict__ svT,
            const u16* __restrict__ mv2T, const float* __restrict__ zi,
            u16* __restrict__ muh, u16* __restrict__ sgh){
  extern __shared__ u16 lds2[];
  u16* Tk  = lds2;
  u16* Tsk = lds2 + 4096;
  u16* Tsq = lds2 + 8192;
  u16* Tmv = lds2 + 12288;
  u16* Tsv = lds2 + 16384;
  u16* Tm2 = lds2 + 20480;
  const int tid = threadIdx.x;
  const int w = tid>>6, l = tid&63, l15 = l&15, g = l>>4;
  u16* Pw = lds2 + 24576 + (w<<11);
  u16* Pg = Pw + 1024;
  const int q0 = blockIdx.x<<7, h = blockIdx.y, b = blockIdx.z;
  const long bS = (long)b*SN;

  // constant A-fragments (wave's 16 q-rows)
  bf16x8 amq[2], acb[2], amk2[2];
  {
    long qrow = (bS + q0 + (w<<4) + l15) * EN;
    #pragma unroll
    for (int s=0;s<2;++s){
      int eoff = (h<<6) + (s<<5) + (g<<3);
      bf16x8 q8 = *(const bf16x8*)(qh + qrow + eoff);
      bf16x8 k8 = *(const bf16x8*)(kh + qrow + eoff);
      bf16x8 s8 = *(const bf16x8*)(sqd + qrow + eoff);
      amq[s] = q8;
      bf16x8 t2, tc;
      #pragma unroll
      for (int j=0;j<8;++j){
        float kv = b2f((u16)k8[j]);
        t2[j] = (short)f2b(kv*kv);
        float qv = b2f((u16)q8[j]);
        float sv = b2f((u16)s8[j]) * 64.0f;
        tc[j] = (short)f2b(qv*qv + sv);
      }
      amk2[s] = t2; acb[s] = tc;
    }
  }
  float zl[4];
  {
    long zbase = (((long)(b*HN+h))<<10) + q0 + (w<<4) + (g<<2);
    #pragma unroll
    for (int r=0;r<4;++r) zl[r] = zi[zbase + r];
  }

  const u16* khb = kh  + bS*EN + (h<<6);
  const u16* skb = skd + bS*EN + (h<<6);
  const u16* sqb = sqd + bS*EN + (h<<6);
  const long hb64 = ((long)(b*HN+h))<<6;
  const u16* mvb = mvT  + hb64*SN;
  const u16* svb = svT  + hb64*SN;
  const u16* m2b = mv2T + hb64*SN;

  f32x4 accM[4], acc2[4], acc3[4];
  #pragma unroll
  for (int t=0;t<4;++t){
    accM[t][0]=0;accM[t][1]=0;accM[t][2]=0;accM[t][3]=0;
    acc2[t][0]=0;acc2[t][1]=0;acc2[t][2]=0;acc2[t][3]=0;
    acc3[t][0]=0;acc3[t][1]=0;acc3[t][2]=0;acc3[t][3]=0;
  }

  const int srow = tid>>3, sseg = tid&7;
  const int a16o = (((srow<<3) + (sseg ^ (srow&7)))<<3);

  for (int kt=0; kt<16; ++kt){
    __syncthreads();
    {
      long off1 = (long)((kt<<6)+srow)*EN + (sseg<<3);
      long off2 = (long)srow*SN + (kt<<6) + (sseg<<3);
      bf16x8 v0 = *(const bf16x8*)(khb+off1);
      bf16x8 v1 = *(const bf16x8*)(skb+off1);
      bf16x8 v2 = *(const bf16x8*)(sqb+off1);
      bf16x8 v3 = *(const bf16x8*)(mvb+off2);
      bf16x8 v4 = *(const bf16x8*)(svb+off2);
      bf16x8 v5 = *(const bf16x8*)(m2b+off2);
      *(bf16x8*)(Tk +a16o) = v0;
      *(bf16x8*)(Tsk+a16o) = v1;
      *(bf16x8*)(Tsq+a16o) = v2;
      *(bf16x8*)(Tmv+a16o) = v3;
      *(bf16x8*)(Tsv+a16o) = v4;
      *(bf16x8*)(Tm2+a16o) = v5;
    }
    __syncthreads();

    f32x4 smu[4], ssg[4];
    #pragma unroll
    for (int t=0;t<4;++t){
      smu[t][0]=0;smu[t][1]=0;smu[t][2]=0;smu[t][3]=0;
      ssg[t][0]=0;ssg[t][1]=0;ssg[t][2]=0;ssg[t][3]=0;
    }
    #pragma unroll
    for (int s=0;s<2;++s){
      int sg=(s<<2)+g;
      #pragma unroll
      for (int t=0;t<4;++t){
        int rn = (t<<4)+l15;
        smu[t] = mfma16(amq[s],  ldsr(Tk, rn,sg), smu[t]);
        ssg[t] = mfma16(acb[s],  ldsr(Tsk,rn,sg), ssg[t]);
        ssg[t] = mfma16(amk2[s], ldsr(Tsq,rn,sg), ssg[t]);
      }
    }
    // S -> P (own-wave LDS; no barrier needed before own-wave read-back)
    #pragma unroll
    for (int t=0;t<4;++t){
      #pragma unroll
      for (int r=0;r<4;++r){
        float e  = __expf(smu[t][r]*0.125f);
        float wv = e*zl[r];
        float u  = wv - wv*wv;
        float sw = u*u*ssg[t][r]*(1.0f/65536.0f);
        int prow = (g<<2)+r, pcol = (t<<4)+l15;
        int off = (((prow<<3) + ((pcol>>3) ^ (prow&7)))<<3) + (pcol&7);
        Pw[off] = f2b(wv);
        Pg[off] = f2b(sw);
      }
    }
    asm volatile("s_waitcnt lgkmcnt(0)" ::: "memory");
    #pragma unroll
    for (int s=0;s<2;++s){
      int sg=(s<<2)+g;
      bf16x8 aw = ldsr(Pw, l15, sg);
      bf16x8 ag = ldsr(Pg, l15, sg);
      bf16x8 pa;                                  // w^2 + Sw
      #pragma unroll
      for (int j=0;j<8;++j){
        float wf = b2f((u16)aw[j]);
        pa[j] = (short)f2b(wf*wf + b2f((u16)ag[j]));
      }
      #pragma unroll
      for (int t=0;t<4;++t){
        int rn = (t<<4)+l15;
        accM[t] = mfma16(aw, ldsr(Tmv,rn,sg), accM[t]);
        acc2[t] = mfma16(pa, ldsr(Tsv,rn,sg), acc2[t]);
        acc3[t] = mfma16(ag, ldsr(Tm2,rn,sg), acc3[t]);
      }
    }
  }
  long grow0 = bS + q0 + (w<<4) + (g<<2);
  #pragma unroll
  for (int t=0;t<4;++t){
    int col = (h<<6) + (t<<4) + l15;
    #pragma unroll
    for (int r=0;r<4;++r){
      long o = (grow0 + r)*EN + col;
      muh[o] = f2b(accM[t][r]);
      sgh[o] = f2b(sp_f((acc2[t][r]+acc3[t][r])*(1.0f/1024.0f)));
    }
  }
}

// ---- per-row combined scalar ----
__global__ void k_rows(const u16* __restrict__ muh, const u16* __restrict__ sgh,
                       float* __restrict__ rcomb){
  __shared__ float tmp[4];
  int r = blockIdx.x;
  const u16* m = muh + (long)r*EN;
  const u16* s = sgh + (long)r*EN;
  float s1=0.f, s2=0.f;
  for (int j=threadIdx.x; j<EN; j+=256){ float a=b2f(m[j]); s1+=a*a; s2+=b2f(s[j]); }
  float r1 = blk_reduce(s1, tmp);
  float r2 = blk_reduce(s2, tmp);
  if (threadIdx.x==0) rcomb[r] = r1*(1.0f/589824.0f) + r2*(1.0f/768.0f);
}

// ---- output linear with fused Sigma epilogue ----
__global__ __launch_bounds__(256)
void k_outmm(const u16* __restrict__ muh, const u16* __restrict__ sgh,
             const u16* __restrict__ WTo, const float* __restrict__ rcomb,
             const float* __restrict__ wso, float* __restrict__ mu_out,
             float* __restrict__ sg_out){
  __shared__ __align__(16) u16 lds[12288];
  u16* Am = lds; u16* As = lds + 4096; u16* Bt = lds + 8192;
  const int tid = threadIdx.x;
  const int w = tid>>6, l = tid&63, l15 = l&15, g = l>>4;
  const int m0 = blockIdx.y<<6, n0 = blockIdx.x<<6;
  f32x4 accM[4], accS[4];
  #pragma unroll
  for (int t=0;t<4;++t){
    accM[t][0]=0;accM[t][1]=0;accM[t][2]=0;accM[t][3]=0;
    accS[t][0]=0;accS[t][1]=0;accS[t][2]=0;accS[t][3]=0;
  }
  for (int k0=0; k0<EN; k0+=64){
    __syncthreads();
    stage64(Am, muh + (long)m0*EN + k0, EN, tid);
    stage64(As, sgh + (long)m0*EN + k0, EN, tid);
    stage64(Bt, WTo + (long)n0*EN + k0, EN, tid);
    __syncthreads();
    #pragma unroll
    for (int s=0;s<2;++s){
      int sg=(s<<2)+g;
      bf16x8 am = ldsr(Am, (w<<4)+l15, sg);
      bf16x8 as = ldsr(As, (w<<4)+l15, sg);
      #pragma unroll
      for (int t=0;t<4;++t){
        bf16x8 bw = ldsr(Bt,(t<<4)+l15,sg);
        bf16x8 b2;
        #pragma unroll
        for (int j=0;j<8;++j){ float f=b2f((u16)bw[j]); b2[j]=(short)f2b(f*f); }
        accM[t] = mfma16(am, bw, accM[t]);
        accS[t] = mfma16(as, b2, accS[t]);
      }
    }
  }
  float rc4[4];
  #pragma unroll
  for (int r=0;r<4;++r) rc4[r] = rcomb[m0 + (w<<4) + (g<<2) + r];
  #pragma unroll
  for (int t=0;t<4;++t){
    int col = n0 + (t<<4) + l15;
    float wsc = wso[col];
    #pragma unroll
    for (int r=0;r<4;++r){
      long row = m0 + (w<<4) + (g<<2) + r;
      mu_out[row*EN + col] = accM[t][r];
      float spre = accS[t][r]*(1.0f/768.0f) + rc4[r]*wsc;
      sg_out[row*EN + col] = sp_f(sp_f(spre));
    }
  }
}

// ---- KL finalize ----
__global__ void k_klf(const float* __restrict__ klacc, float* __restrict__ out){
  float Smu2 = klacc[0], Ssig = klacc[1], Ssp = klacc[2];
  const float C = -5.60517018599f;
  out[0] = 0.5f*(4.f*C - Ssig*(1.0f/768.0f) + Ssp*(1.0f/7.68f) + Smu2*(1.0f/5898.24f));
}

extern "C" void kernel_launch(void* const* d_in, const int* in_sizes, int n_in,
                              void* d_out, int out_size, void* d_ws, size_t ws_size,
                              hipStream_t stream) {
  (void)in_sizes; (void)n_in; (void)out_size; (void)ws_size;
  const float* x      = (const float*)d_in[0];
  const float* wq_mu  = (const float*)d_in[1];
  const float* wq_sig = (const float*)d_in[2];
  const float* wk_mu  = (const float*)d_in[3];
  const float* wk_sig = (const float*)d_in[4];
  const float* wv_mu  = (const float*)d_in[5];
  const float* wv_sig = (const float*)d_in[6];
  const float* wo_mu  = (const float*)d_in[7];
  const float* wo_sig = (const float*)d_in[8];

  char* wsb = (char*)d_ws;
  float* xx    = (float*)(wsb + OFF_XX);
  float* rc    = (float*)(wsb + OFF_RC);
  float* wsig  = (float*)(wsb + OFF_WSIG);
  float* kla   = (float*)(wsb + OFF_KL);
  float* zi    = (float*)(wsb + OFF_ZI);
  u16*   WT    = (u16*)(wsb + OFF_WT);
  u16*   qh    = (u16*)(wsb + OFF_QH);
  u16*   kh    = (u16*)(wsb + OFF_KH);
  u16*   sqd   = (u16*)(wsb + OFF_SQD);
  u16*   skd   = (u16*)(wsb + OFF_SKD);
  u16*   mvT   = (u16*)(wsb + OFF_MVT);
  u16*   mv2T  = (u16*)(wsb + OFF_MV2);
  u16*   svT   = (u16*)(wsb + OFF_SVT);
  u16*   muh   = (u16*)(wsb + OFF_MUH);
  u16*   sgh   = (u16*)(wsb + OFF_SGH);

  float* mu_out = (float*)d_out;
  float* sg_out = mu_out + BSE;
  float* kl_out = mu_out + 2*BSE;

  (void)hipMemsetAsync(kla, 0, 3*sizeof(float), stream);
  k_prep<<<4, 256, 0, stream>>>(wq_sig, wk_sig, wv_sig, wo_sig, wsig, kla);
  k_xx<<<BSN, 256, 0, stream>>>(x, xx);
  k_mu2<<<dim3(64,4), 256, 0, stream>>>(wq_mu, wk_mu, wv_mu, wo_mu, kla);
  k_wt<<<dim3(12,12,4), 256, 0, stream>>>(wq_mu, wk_mu, wv_mu, wo_mu, WT);
  k_sigarr<<<BSN, 256, 0, stream>>>(xx, wsig, sqd, skd);
  k_svt<<<dim3(16,HN,4), 256, 0, stream>>>(xx, wsig, svT);
  k_projmm<<<dim3(12,64,3), 256, 0, stream>>>(x, WT, qh, kh, mvT, mv2T);
  k_z<<<dim3(16,HN,4), 256, 0, stream>>>(qh, kh, zi);

  const int attn_lds = 40960*2;
  (void)hipFuncSetAttribute((const void*)k_attn,
                      hipFuncAttributeMaxDynamicSharedMemorySize, attn_lds);
  k_attn<<<dim3(8,HN,4), 512, attn_lds, stream>>>(qh, kh, sqd, skd, mvT, svT,
                                                  mv2T, zi, muh, sgh);
  k_rows<<<BSN, 256, 0, stream>>>(muh, sgh, rc);
  k_outmm<<<dim3(12,64), 256, 0, stream>>>(muh, sgh, WT + 3l*589824, rc,
                                           wsig + 3*EN, mu_out, sg_out);
  k_klf<<<1, 1, 0, stream>>>(kla, kl_out);
}

// Round 5
// 378.340 us; speedup vs baseline: 6.3935x; 1.1552x over previous
//
#include <hip/hip_runtime.h>
#include <math.h>

#define EN 768
#define SN 1024
#define HN 12
#define BSN 4096
#define BSE 3145728

typedef __attribute__((ext_vector_type(8))) short bf16x8;
typedef __attribute__((ext_vector_type(4))) float f32x4;
typedef __attribute__((ext_vector_type(4))) unsigned short u16x4;
typedef unsigned short u16;

// ---- workspace byte offsets (~58.8 MB) ----
#define OFF_XX   0u
#define OFF_RC   16384u
#define OFF_WSIG 32768u
#define OFF_KL   45056u
#define OFF_ZI   49152u       // [4*12*1024] f32 zinv
#define OFF_WT   262144u      // 4 * 768*768 u16
#define OFF_QH   4980736u
#define OFF_KH   11272192u
#define OFF_SQD  17563648u
#define OFF_SKD  23855104u
#define OFF_MVT  30146560u
#define OFF_MV2  36438016u
#define OFF_SVT  42729472u
#define OFF_MUH  49020928u
#define OFF_SGH  55312384u

__device__ __forceinline__ float sp_f(float x){
  return fmaxf(x, 0.f) + log1pf(__expf(-fabsf(x)));
}
__device__ __forceinline__ u16 f2b(float f){
  unsigned u = __float_as_uint(f);
  return (u16)((u + 0x7fffu + ((u>>16)&1u)) >> 16);
}
__device__ __forceinline__ float b2f(u16 h){
  return __uint_as_float(((unsigned)h)<<16);
}
__device__ __forceinline__ f32x4 mfma16(bf16x8 a, bf16x8 b, f32x4 c){
  return __builtin_amdgcn_mfma_f32_16x16x32_bf16(a, b, c, 0, 0, 0);
}
// LDS frag read from swizzled [rows][64] bf16 tile
__device__ __forceinline__ bf16x8 ldsr(const u16* t, int row, int sg){
  int a16 = (row<<3) + (sg ^ (row&7));
  return *(const bf16x8*)(t + (a16<<3));
}
// stage 64x64 bf16 tile with 256 threads (2 slots/thread)
__device__ __forceinline__ void stage64(u16* dst, const u16* src, int rstride, int tid){
  #pragma unroll
  for (int it=0; it<2; ++it){
    int idx = (it<<8) + tid;
    int row = idx>>3, seg = idx&7;
    bf16x8 v = *(const bf16x8*)(src + (long)row*rstride + (seg<<3));
    int a16 = (row<<3) + (seg ^ (row&7));
    *(bf16x8*)(dst + (a16<<3)) = v;
  }
}

__device__ __forceinline__ float blk_reduce(float v, float* tmp){
  #pragma unroll
  for (int off = 32; off; off >>= 1) v += __shfl_down(v, off, 64);
  int w = threadIdx.x >> 6;
  if ((threadIdx.x & 63) == 0) tmp[w] = v;
  __syncthreads();
  float r = 0.f;
  if (threadIdx.x == 0) r = tmp[0] + tmp[1] + tmp[2] + tmp[3];
  __syncthreads();
  return r;
}

// ---- softplus(w_sigma) + KL sigma terms ----
__global__ void k_prep(const float* __restrict__ s0, const float* __restrict__ s1,
                       const float* __restrict__ s2, const float* __restrict__ s3,
                       float* __restrict__ wsig, float* __restrict__ klacc){
  __shared__ float tmp[4];
  const float* src = (blockIdx.x==0)?s0:(blockIdx.x==1)?s1:(blockIdx.x==2)?s2:s3;
  int l = blockIdx.x;
  float ssum=0.f, spsum=0.f;
  for (int j=threadIdx.x; j<EN; j+=256){
    float sg = src[j];
    float w  = log1pf(__expf(sg));
    wsig[l*EN+j] = w;
    ssum += sg; spsum += w;
  }
  float a = blk_reduce(ssum, tmp);
  float b = blk_reduce(spsum, tmp);
  if (threadIdx.x==0){ atomicAdd(&klacc[1], a); atomicAdd(&klacc[2], b); }
}

// ---- xx[r] = sum_e (x/768)^2 ----
__global__ void k_xx(const float* __restrict__ x, float* __restrict__ xx){
  __shared__ float tmp[4];
  int r = blockIdx.x;
  const float* xr = x + (long)r*EN;
  float s=0.f;
  for (int j=threadIdx.x; j<EN; j+=256){ float v = xr[j]; s += v*v; }
  float t = blk_reduce(s, tmp);
  if (threadIdx.x==0) xx[r] = t*(1.0f/589824.0f);
}

// ---- KL mu^2 ----
__global__ void k_mu2(const float* __restrict__ w0, const float* __restrict__ w1,
                      const float* __restrict__ w2, const float* __restrict__ w3,
                      float* __restrict__ klacc){
  __shared__ float tmp[4];
  const float* w = (blockIdx.y==0)?w0:(blockIdx.y==1)?w1:(blockIdx.y==2)?w2:w3;
  const float4* w4 = (const float4*)w;
  float s=0.f;
  for (int i=blockIdx.x*256+threadIdx.x; i<147456; i+=gridDim.x*256){
    float4 v = w4[i];
    s += v.x*v.x + v.y*v.y + v.z*v.z + v.w*v.w;
  }
  float r = blk_reduce(s, tmp);
  if (threadIdx.x==0) atomicAdd(&klacc[0], r);
}

// ---- transpose weights to bf16 ----
__global__ void k_wt(const float* __restrict__ w0, const float* __restrict__ w1,
                     const float* __restrict__ w2, const float* __restrict__ w3,
                     u16* __restrict__ wt){
  __shared__ float t[64*65];
  const float* W = (blockIdx.z==0)?w0:(blockIdx.z==1)?w1:(blockIdx.z==2)?w2:w3;
  u16* WT = wt + (long)blockIdx.z*589824;
  int r0 = blockIdx.y<<6, c0 = blockIdx.x<<6;
  int tid = threadIdx.x;
  #pragma unroll
  for (int it=0; it<16; ++it){
    int idx=(it<<8)+tid; int r=idx>>6, c=idx&63;
    t[c*65+r] = W[(long)(r0+r)*EN + c0+c];
  }
  __syncthreads();
  #pragma unroll
  for (int it=0; it<16; ++it){
    int idx=(it<<8)+tid; int c=idx>>6, r=idx&63;
    WT[(long)(c0+c)*EN + r0+r] = f2b(t[c*65+r]);
  }
}

// ---- sq/64, sk/64 arrays ----
__global__ void k_sigarr(const float* __restrict__ xx, const float* __restrict__ wsig,
                         u16* __restrict__ sqd, u16* __restrict__ skd){
  int r = blockIdx.x;
  float xr = xx[r];
  for (int c=threadIdx.x; c<EN; c+=256){
    sqd[(long)r*EN+c] = f2b(sp_f(xr*wsig[c])*(1.0f/64.0f));
    skd[(long)r*EN+c] = f2b(sp_f(xr*wsig[EN+c])*(1.0f/64.0f));
  }
}

// ---- svT[b,h][d][k] = softplus(xx[b,k]*wsig_v[h,d]) ----
__global__ void k_svt(const float* __restrict__ xx, const float* __restrict__ wsig,
                      u16* __restrict__ svT){
  __shared__ float sxx[64], swv[64];
  int kt=blockIdx.x, h=blockIdx.y, b=blockIdx.z, tid=threadIdx.x;
  if (tid < 64){
    sxx[tid] = xx[(long)b*SN + (kt<<6) + tid];
    swv[tid] = wsig[2*EN + (h<<6) + tid];
  }
  __syncthreads();
  long obase = (((long)(b*HN+h))<<6)*SN + (kt<<6);
  #pragma unroll
  for (int it=0; it<16; ++it){
    int idx=(it<<8)+tid; int d=idx>>6, k=idx&63;
    svT[obase + (long)d*SN + k] = f2b(sp_f(sxx[k]*swv[d]));
  }
}

// ---- projections via MFMA; z=2 (v) writes transposed mvT + mv2T ----
__global__ __launch_bounds__(256)
void k_projmm(const float* __restrict__ x, const u16* __restrict__ WT,
              u16* __restrict__ oq, u16* __restrict__ ok,
              u16* __restrict__ mvT, u16* __restrict__ mv2T){
  __shared__ __align__(16) u16 lds[8192];
  u16* At = lds; u16* Bt = lds + 4096;
  const int tid = threadIdx.x;
  const int w = tid>>6, l = tid&63, l15 = l&15, g = l>>4;
  const int m0 = blockIdx.y<<6, n0 = blockIdx.x<<6;
  const u16* Wt = WT + (long)blockIdx.z*589824;
  f32x4 acc[4];
  #pragma unroll
  for (int t=0;t<4;++t){ acc[t][0]=0;acc[t][1]=0;acc[t][2]=0;acc[t][3]=0; }
  for (int k0=0; k0<EN; k0+=64){
    __syncthreads();
    #pragma unroll
    for (int it=0; it<2; ++it){
      int idx=(it<<8)+tid; int row=idx>>3, seg=idx&7;
      const float* sp = x + (long)(m0+row)*EN + k0 + (seg<<3);
      float4 a = *(const float4*)sp; float4 c = *(const float4*)(sp+4);
      bf16x8 v;
      v[0]=(short)f2b(a.x); v[1]=(short)f2b(a.y); v[2]=(short)f2b(a.z); v[3]=(short)f2b(a.w);
      v[4]=(short)f2b(c.x); v[5]=(short)f2b(c.y); v[6]=(short)f2b(c.z); v[7]=(short)f2b(c.w);
      int a16=(row<<3)+(seg^(row&7));
      *(bf16x8*)(At + (a16<<3)) = v;
    }
    stage64(Bt, Wt + (long)n0*EN + k0, EN, tid);
    __syncthreads();
    #pragma unroll
    for (int s=0;s<2;++s){
      int sg=(s<<2)+g;
      bf16x8 af = ldsr(At, (w<<4)+l15, sg);
      #pragma unroll
      for (int t=0;t<4;++t)
        acc[t] = mfma16(af, ldsr(Bt,(t<<4)+l15,sg), acc[t]);
    }
  }
  if (blockIdx.z < 2){
    u16* out = blockIdx.z ? ok : oq;
    #pragma unroll
    for (int t=0;t<4;++t){
      int col = n0 + (t<<4) + l15;
      #pragma unroll
      for (int r=0;r<4;++r){
        long row = m0 + (w<<4) + (g<<2) + r;
        out[row*EN + col] = f2b(acc[t][r]);
      }
    }
  } else {
    int b  = m0 >> 10;
    int hh = n0 >> 6;
    long obase = (((long)(b*HN+hh))<<6)*SN;
    int tok0 = (m0 & 1023) + (w<<4) + (g<<2);
    #pragma unroll
    for (int t=0;t<4;++t){
      int d = (t<<4) + l15;
      u16x4 m4, s4;
      #pragma unroll
      for (int r=0;r<4;++r){
        u16 mb = f2b(acc[t][r]);
        m4[r] = mb;
        float mf = b2f(mb);
        s4[r] = f2b(mf*mf);
      }
      *(u16x4*)&mvT[obase + (long)d*SN + tok0]  = m4;
      *(u16x4*)&mv2T[obase + (long)d*SN + tok0] = s4;
    }
  }
}

// ---- Z kernel: zinv[b,h,q] = 1 / sum_k exp(mu_score/8); XCD-swizzled 1-D grid ----
__global__ __launch_bounds__(256)
void k_z(const u16* __restrict__ qh, const u16* __restrict__ kh,
         float* __restrict__ zi){
  __shared__ __align__(16) u16 Tk[4096];
  const int tid = threadIdx.x;
  const int w = tid>>6, l = tid&63, l15 = l&15, g = l>>4;
  // 768 blocks: xcd = i&7 gets 6 (b,h) pairs x 16 q-tiles
  const int i = blockIdx.x;
  const int xcd = i & 7, slot = i >> 3;
  const int qt = slot & 15;
  const int pair = xcd*6 + (slot >> 4);
  const int h = pair % HN, b = pair / HN;
  const int q0 = qt<<6;
  const long bS = (long)b*SN;
  bf16x8 amq[2];
  {
    long qrow = (bS + q0 + (w<<4) + l15) * EN;
    #pragma unroll
    for (int s=0;s<2;++s)
      amq[s] = *(const bf16x8*)(qh + qrow + (h<<6) + (s<<5) + (g<<3));
  }
  const u16* khb = kh + bS*EN + (h<<6);
  f32x4 zacc = {0.f,0.f,0.f,0.f};
  for (int kt=0; kt<16; ++kt){
    __syncthreads();
    stage64(Tk, khb + (long)(kt<<6)*EN, EN, tid);
    __syncthreads();
    f32x4 smu[4];
    #pragma unroll
    for (int t=0;t<4;++t){ smu[t][0]=0;smu[t][1]=0;smu[t][2]=0;smu[t][3]=0; }
    #pragma unroll
    for (int s=0;s<2;++s){
      int sg=(s<<2)+g;
      #pragma unroll
      for (int t=0;t<4;++t)
        smu[t] = mfma16(amq[s], ldsr(Tk,(t<<4)+l15,sg), smu[t]);
    }
    #pragma unroll
    for (int t=0;t<4;++t)
      #pragma unroll
      for (int r=0;r<4;++r)
        zacc[r] += __expf(smu[t][r]*0.125f);
  }
  #pragma unroll
  for (int m=1; m<16; m<<=1){
    #pragma unroll
    for (int r=0;r<4;++r) zacc[r] += __shfl_xor(zacc[r], m, 64);
  }
  if (l15 == 0){
    long zbase = (((long)(b*HN+h))<<10) + q0 + (w<<4) + (g<<2);
    #pragma unroll
    for (int r=0;r<4;++r) zi[zbase + r] = 1.0f/zacc[r];
  }
}

// ---- single-pass fused Bayesian attention; 8 waves, q-tile 128, 80KB LDS ----
// __launch_bounds__(512,2): 2 blocks/CU -> VGPR cap 128 (no spill; round-4's
// (512,4) capped at 64 VGPR and spilled ~500MB to scratch).
__global__ __launch_bounds__(512, 2)
void k_attn(const u16* __restrict__ qh, const u16* __restrict__ kh,
            const u16* __restrict__ sqd, const u16* __restrict__ skd,
            const u16* __restrict__ mvT, const u16* __restrict__ svT,
            const u16* __restrict__ mv2T, const float* __restrict__ zi,
            u16* __restrict__ muh, u16* __restrict__ sgh){
  extern __shared__ u16 lds2[];
  u16* Tk  = lds2;
  u16* Tsk = lds2 + 4096;
  u16* Tsq = lds2 + 8192;
  u16* Tmv = lds2 + 12288;
  u16* Tsv = lds2 + 16384;
  u16* Tm2 = lds2 + 20480;
  const int tid = threadIdx.x;
  const int w = tid>>6, l = tid&63, l15 = l&15, g = l>>4;
  u16* Pw = lds2 + 24576 + (w<<11);
  u16* Pg = Pw + 1024;
  // XCD swizzle: 384 blocks = 8 XCDs x 6 (b,h) pairs x 8 q-tiles
  const int i = blockIdx.x;
  const int xcd = i & 7, slot = i >> 3;
  const int qt = slot & 7;
  const int pair = xcd*6 + (slot >> 3);
  const int h = pair % HN, b = pair / HN;
  const int q0 = qt<<7;
  const long bS = (long)b*SN;

  // constant A-fragments (wave's 16 q-rows)
  bf16x8 amq[2], acb[2], amk2[2];
  {
    long qrow = (bS + q0 + (w<<4) + l15) * EN;
    #pragma unroll
    for (int s=0;s<2;++s){
      int eoff = (h<<6) + (s<<5) + (g<<3);
      bf16x8 q8 = *(const bf16x8*)(qh + qrow + eoff);
      bf16x8 k8 = *(const bf16x8*)(kh + qrow + eoff);
      bf16x8 s8 = *(const bf16x8*)(sqd + qrow + eoff);
      amq[s] = q8;
      bf16x8 t2, tc;
      #pragma unroll
      for (int j=0;j<8;++j){
        float kv = b2f((u16)k8[j]);
        t2[j] = (short)f2b(kv*kv);
        float qv = b2f((u16)q8[j]);
        float sv = b2f((u16)s8[j]) * 64.0f;
        tc[j] = (short)f2b(qv*qv + sv);
      }
      amk2[s] = t2; acb[s] = tc;
    }
  }
  float zl[4];
  {
    long zbase = (((long)(b*HN+h))<<10) + q0 + (w<<4) + (g<<2);
    #pragma unroll
    for (int r=0;r<4;++r) zl[r] = zi[zbase + r];
  }

  const u16* khb = kh  + bS*EN + (h<<6);
  const u16* skb = skd + bS*EN + (h<<6);
  const u16* sqb = sqd + bS*EN + (h<<6);
  const long hb64 = ((long)(b*HN+h))<<6;
  const u16* mvb = mvT  + hb64*SN;
  const u16* svb = svT  + hb64*SN;
  const u16* m2b = mv2T + hb64*SN;

  f32x4 accM[4], acc2[4], acc3[4];
  #pragma unroll
  for (int t=0;t<4;++t){
    accM[t][0]=0;accM[t][1]=0;accM[t][2]=0;accM[t][3]=0;
    acc2[t][0]=0;acc2[t][1]=0;acc2[t][2]=0;acc2[t][3]=0;
    acc3[t][0]=0;acc3[t][1]=0;acc3[t][2]=0;acc3[t][3]=0;
  }

  const int srow = tid>>3, sseg = tid&7;
  const int a16o = (((srow<<3) + (sseg ^ (srow&7)))<<3);

  for (int kt=0; kt<16; ++kt){
    __syncthreads();
    {
      long off1 = (long)((kt<<6)+srow)*EN + (sseg<<3);
      long off2 = (long)srow*SN + (kt<<6) + (sseg<<3);
      bf16x8 v0 = *(const bf16x8*)(khb+off1);
      bf16x8 v1 = *(const bf16x8*)(skb+off1);
      bf16x8 v2 = *(const bf16x8*)(sqb+off1);
      bf16x8 v3 = *(const bf16x8*)(mvb+off2);
      bf16x8 v4 = *(const bf16x8*)(svb+off2);
      bf16x8 v5 = *(const bf16x8*)(m2b+off2);
      *(bf16x8*)(Tk +a16o) = v0;
      *(bf16x8*)(Tsk+a16o) = v1;
      *(bf16x8*)(Tsq+a16o) = v2;
      *(bf16x8*)(Tmv+a16o) = v3;
      *(bf16x8*)(Tsv+a16o) = v4;
      *(bf16x8*)(Tm2+a16o) = v5;
    }
    __syncthreads();

    // score phase, serialized over t (keeps live smu/ssg at 8 VGPRs)
    #pragma unroll
    for (int t=0;t<4;++t){
      f32x4 smu = {0.f,0.f,0.f,0.f}, ssg = {0.f,0.f,0.f,0.f};
      #pragma unroll
      for (int s=0;s<2;++s){
        int sg=(s<<2)+g;
        int rn = (t<<4)+l15;
        smu = mfma16(amq[s],  ldsr(Tk, rn,sg), smu);
        ssg = mfma16(acb[s],  ldsr(Tsk,rn,sg), ssg);
        ssg = mfma16(amk2[s], ldsr(Tsq,rn,sg), ssg);
      }
      #pragma unroll
      for (int r=0;r<4;++r){
        float e  = __expf(smu[r]*0.125f);
        float wv = e*zl[r];
        float u  = wv - wv*wv;
        float sw = u*u*ssg[r]*(1.0f/65536.0f);
        int prow = (g<<2)+r, pcol = (t<<4)+l15;
        int off = (((prow<<3) + ((pcol>>3) ^ (prow&7)))<<3) + (pcol&7);
        Pw[off] = f2b(wv);
        Pg[off] = f2b(sw);
      }
    }
    asm volatile("s_waitcnt lgkmcnt(0)" ::: "memory");
    #pragma unroll
    for (int s=0;s<2;++s){
      int sg=(s<<2)+g;
      bf16x8 aw = ldsr(Pw, l15, sg);
      bf16x8 ag = ldsr(Pg, l15, sg);
      bf16x8 pa;                                  // w^2 + Sw
      #pragma unroll
      for (int j=0;j<8;++j){
        float wf = b2f((u16)aw[j]);
        pa[j] = (short)f2b(wf*wf + b2f((u16)ag[j]));
      }
      #pragma unroll
      for (int t=0;t<4;++t){
        int rn = (t<<4)+l15;
        accM[t] = mfma16(aw, ldsr(Tmv,rn,sg), accM[t]);
        acc2[t] = mfma16(pa, ldsr(Tsv,rn,sg), acc2[t]);
        acc3[t] = mfma16(ag, ldsr(Tm2,rn,sg), acc3[t]);
      }
    }
  }
  long grow0 = bS + q0 + (w<<4) + (g<<2);
  #pragma unroll
  for (int t=0;t<4;++t){
    int col = (h<<6) + (t<<4) + l15;
    #pragma unroll
    for (int r=0;r<4;++r){
      long o = (grow0 + r)*EN + col;
      muh[o] = f2b(accM[t][r]);
      sgh[o] = f2b(sp_f((acc2[t][r]+acc3[t][r])*(1.0f/1024.0f)));
    }
  }
}

// ---- per-row combined scalar ----
__global__ void k_rows(const u16* __restrict__ muh, const u16* __restrict__ sgh,
                       float* __restrict__ rcomb){
  __shared__ float tmp[4];
  int r = blockIdx.x;
  const u16* m = muh + (long)r*EN;
  const u16* s = sgh + (long)r*EN;
  float s1=0.f, s2=0.f;
  for (int j=threadIdx.x; j<EN; j+=256){ float a=b2f(m[j]); s1+=a*a; s2+=b2f(s[j]); }
  float r1 = blk_reduce(s1, tmp);
  float r2 = blk_reduce(s2, tmp);
  if (threadIdx.x==0) rcomb[r] = r1*(1.0f/589824.0f) + r2*(1.0f/768.0f);
}

// ---- output linear with fused Sigma epilogue ----
__global__ __launch_bounds__(256)
void k_outmm(const u16* __restrict__ muh, const u16* __restrict__ sgh,
             const u16* __restrict__ WTo, const float* __restrict__ rcomb,
             const float* __restrict__ wso, float* __restrict__ mu_out,
             float* __restrict__ sg_out){
  __shared__ __align__(16) u16 lds[12288];
  u16* Am = lds; u16* As = lds + 4096; u16* Bt = lds + 8192;
  const int tid = threadIdx.x;
  const int w = tid>>6, l = tid&63, l15 = l&15, g = l>>4;
  const int m0 = blockIdx.y<<6, n0 = blockIdx.x<<6;
  f32x4 accM[4], accS[4];
  #pragma unroll
  for (int t=0;t<4;++t){
    accM[t][0]=0;accM[t][1]=0;accM[t][2]=0;accM[t][3]=0;
    accS[t][0]=0;accS[t][1]=0;accS[t][2]=0;accS[t][3]=0;
  }
  for (int k0=0; k0<EN; k0+=64){
    __syncthreads();
    stage64(Am, muh + (long)m0*EN + k0, EN, tid);
    stage64(As, sgh + (long)m0*EN + k0, EN, tid);
    stage64(Bt, WTo + (long)n0*EN + k0, EN, tid);
    __syncthreads();
    #pragma unroll
    for (int s=0;s<2;++s){
      int sg=(s<<2)+g;
      bf16x8 am = ldsr(Am, (w<<4)+l15, sg);
      bf16x8 as = ldsr(As, (w<<4)+l15, sg);
      #pragma unroll
      for (int t=0;t<4;++t){
        bf16x8 bw = ldsr(Bt,(t<<4)+l15,sg);
        bf16x8 b2;
        #pragma unroll
        for (int j=0;j<8;++j){ float f=b2f((u16)bw[j]); b2[j]=(short)f2b(f*f); }
        accM[t] = mfma16(am, bw, accM[t]);
        accS[t] = mfma16(as, b2, accS[t]);
      }
    }
  }
  float rc4[4];
  #pragma unroll
  for (int r=0;r<4;++r) rc4[r] = rcomb[m0 + (w<<4) + (g<<2) + r];
  #pragma unroll
  for (int t=0;t<4;++t){
    int col = n0 + (t<<4) + l15;
    float wsc = wso[col];
    #pragma unroll
    for (int r=0;r<4;++r){
      long row = m0 + (w<<4) + (g<<2) + r;
      mu_out[row*EN + col] = accM[t][r];
      float spre = accS[t][r]*(1.0f/768.0f) + rc4[r]*wsc;
      sg_out[row*EN + col] = sp_f(sp_f(spre));
    }
  }
}

// ---- KL finalize ----
__global__ void k_klf(const float* __restrict__ klacc, float* __restrict__ out){
  float Smu2 = klacc[0], Ssig = klacc[1], Ssp = klacc[2];
  const float C = -5.60517018599f;
  out[0] = 0.5f*(4.f*C - Ssig*(1.0f/768.0f) + Ssp*(1.0f/7.68f) + Smu2*(1.0f/5898.24f));
}

extern "C" void kernel_launch(void* const* d_in, const int* in_sizes, int n_in,
                              void* d_out, int out_size, void* d_ws, size_t ws_size,
                              hipStream_t stream) {
  (void)in_sizes; (void)n_in; (void)out_size; (void)ws_size;
  const float* x      = (const float*)d_in[0];
  const float* wq_mu  = (const float*)d_in[1];
  const float* wq_sig = (const float*)d_in[2];
  const float* wk_mu  = (const float*)d_in[3];
  const float* wk_sig = (const float*)d_in[4];
  const float* wv_mu  = (const float*)d_in[5];
  const float* wv_sig = (const float*)d_in[6];
  const float* wo_mu  = (const float*)d_in[7];
  const float* wo_sig = (const float*)d_in[8];

  char* wsb = (char*)d_ws;
  float* xx    = (float*)(wsb + OFF_XX);
  float* rc    = (float*)(wsb + OFF_RC);
  float* wsig  = (float*)(wsb + OFF_WSIG);
  float* kla   = (float*)(wsb + OFF_KL);
  float* zi    = (float*)(wsb + OFF_ZI);
  u16*   WT    = (u16*)(wsb + OFF_WT);
  u16*   qh    = (u16*)(wsb + OFF_QH);
  u16*   kh    = (u16*)(wsb + OFF_KH);
  u16*   sqd   = (u16*)(wsb + OFF_SQD);
  u16*   skd   = (u16*)(wsb + OFF_SKD);
  u16*   mvT   = (u16*)(wsb + OFF_MVT);
  u16*   mv2T  = (u16*)(wsb + OFF_MV2);
  u16*   svT   = (u16*)(wsb + OFF_SVT);
  u16*   muh   = (u16*)(wsb + OFF_MUH);
  u16*   sgh   = (u16*)(wsb + OFF_SGH);

  float* mu_out = (float*)d_out;
  float* sg_out = mu_out + BSE;
  float* kl_out = mu_out + 2*BSE;

  (void)hipMemsetAsync(kla, 0, 3*sizeof(float), stream);
  k_prep<<<4, 256, 0, stream>>>(wq_sig, wk_sig, wv_sig, wo_sig, wsig, kla);
  k_xx<<<BSN, 256, 0, stream>>>(x, xx);
  k_mu2<<<dim3(64,4), 256, 0, stream>>>(wq_mu, wk_mu, wv_mu, wo_mu, kla);
  k_wt<<<dim3(12,12,4), 256, 0, stream>>>(wq_mu, wk_mu, wv_mu, wo_mu, WT);
  k_sigarr<<<BSN, 256, 0, stream>>>(xx, wsig, sqd, skd);
  k_svt<<<dim3(16,HN,4), 256, 0, stream>>>(xx, wsig, svT);
  k_projmm<<<dim3(12,64,3), 256, 0, stream>>>(x, WT, qh, kh, mvT, mv2T);
  k_z<<<768, 256, 0, stream>>>(qh, kh, zi);

  const int attn_lds = 40960*2;
  (void)hipFuncSetAttribute((const void*)k_attn,
                      hipFuncAttributeMaxDynamicSharedMemorySize, attn_lds);
  k_attn<<<384, 512, attn_lds, stream>>>(qh, kh, sqd, skd, mvT, svT,
                                         mv2T, zi, muh, sgh);
  k_rows<<<BSN, 256, 0, stream>>>(muh, sgh, rc);
  k_outmm<<<dim3(12,64), 256, 0, stream>>>(muh, sgh, WT + 3l*589824, rc,
                                           wsig + 3*EN, mu_out, sg_out);
  k_klf<<<1, 1, 0, stream>>>(kla, kl_out);
}

// Round 6
// 359.230 us; speedup vs baseline: 6.7336x; 1.0532x over previous
//
#include <hip/hip_runtime.h>
#include <math.h>

#define EN 768
#define SN 1024
#define HN 12
#define BSN 4096
#define BSE 3145728

typedef __attribute__((ext_vector_type(8))) short bf16x8;
typedef __attribute__((ext_vector_type(4))) float f32x4;
typedef __attribute__((ext_vector_type(4))) unsigned short u16x4;
typedef __attribute__((ext_vector_type(4))) unsigned int u32x4;
typedef unsigned short u16;

// ---- workspace byte offsets (~58.8 MB) ----
#define OFF_XX   0u
#define OFF_RC   16384u
#define OFF_WSIG 32768u
#define OFF_KL   45056u
#define OFF_ZI   49152u       // [4*12*1024] f32 zinv
#define OFF_WT   262144u      // 4 * 768*768 u16
#define OFF_QH   4980736u
#define OFF_KH   11272192u
#define OFF_SQD  17563648u
#define OFF_SKD  23855104u
#define OFF_MVT  30146560u
#define OFF_MV2  36438016u
#define OFF_SVT  42729472u
#define OFF_MUH  49020928u
#define OFF_SGH  55312384u

__device__ __forceinline__ float sp_f(float x){
  return fmaxf(x, 0.f) + log1pf(__expf(-fabsf(x)));
}
__device__ __forceinline__ u16 f2b(float f){
  unsigned u = __float_as_uint(f);
  return (u16)((u + 0x7fffu + ((u>>16)&1u)) >> 16);
}
__device__ __forceinline__ float b2f(u16 h){
  return __uint_as_float(((unsigned)h)<<16);
}
// packed f32x2 -> bf16x2 in one instruction (RNE, same bits as f2b)
__device__ __forceinline__ unsigned cvtpk(float lo, float hi){
  unsigned r;
  asm("v_cvt_pk_bf16_f32 %0, %1, %2" : "=v"(r) : "v"(lo), "v"(hi));
  return r;
}
__device__ __forceinline__ bf16x8 u2b(u32x4 v){
  union{u32x4 u; bf16x8 b;} x; x.u = v; return x.b;
}
__device__ __forceinline__ f32x4 mfma16(bf16x8 a, bf16x8 b, f32x4 c){
  return __builtin_amdgcn_mfma_f32_16x16x32_bf16(a, b, c, 0, 0, 0);
}
// square a bf16x8 elementwise -> bf16x8 (via cvt_pk)
__device__ __forceinline__ bf16x8 sq8(bf16x8 a){
  union{bf16x8 b; u32x4 u;} x; x.b = a;
  u32x4 r;
  #pragma unroll
  for (int i=0;i<4;++i){
    unsigned v = x.u[i];
    float f0 = __uint_as_float(v<<16);
    float f1 = __uint_as_float(v & 0xffff0000u);
    r[i] = cvtpk(f0*f0, f1*f1);
  }
  return u2b(r);
}
// LDS frag read from swizzled [rows][64] bf16 tile
__device__ __forceinline__ bf16x8 ldsr(const u16* t, int row, int sg){
  int a16 = (row<<3) + (sg ^ (row&7));
  return *(const bf16x8*)(t + (a16<<3));
}
// stage 64x64 bf16 tile with 256 threads (2 slots/thread)
__device__ __forceinline__ void stage64(u16* dst, const u16* src, int rstride, int tid){
  #pragma unroll
  for (int it=0; it<2; ++it){
    int idx = (it<<8) + tid;
    int row = idx>>3, seg = idx&7;
    bf16x8 v = *(const bf16x8*)(src + (long)row*rstride + (seg<<3));
    int a16 = (row<<3) + (seg ^ (row&7));
    *(bf16x8*)(dst + (a16<<3)) = v;
  }
}

__device__ __forceinline__ float blk_reduce(float v, float* tmp){
  #pragma unroll
  for (int off = 32; off; off >>= 1) v += __shfl_down(v, off, 64);
  int w = threadIdx.x >> 6;
  if ((threadIdx.x & 63) == 0) tmp[w] = v;
  __syncthreads();
  float r = 0.f;
  if (threadIdx.x == 0) r = tmp[0] + tmp[1] + tmp[2] + tmp[3];
  __syncthreads();
  return r;
}

// ---- softplus(w_sigma) + KL sigma terms ----
__global__ void k_prep(const float* __restrict__ s0, const float* __restrict__ s1,
                       const float* __restrict__ s2, const float* __restrict__ s3,
                       float* __restrict__ wsig, float* __restrict__ klacc){
  __shared__ float tmp[4];
  const float* src = (blockIdx.x==0)?s0:(blockIdx.x==1)?s1:(blockIdx.x==2)?s2:s3;
  int l = blockIdx.x;
  float ssum=0.f, spsum=0.f;
  for (int j=threadIdx.x; j<EN; j+=256){
    float sg = src[j];
    float w  = log1pf(__expf(sg));
    wsig[l*EN+j] = w;
    ssum += sg; spsum += w;
  }
  float a = blk_reduce(ssum, tmp);
  float b = blk_reduce(spsum, tmp);
  if (threadIdx.x==0){ atomicAdd(&klacc[1], a); atomicAdd(&klacc[2], b); }
}

// ---- xx[r] = sum_e (x/768)^2 ----
__global__ void k_xx(const float* __restrict__ x, float* __restrict__ xx){
  __shared__ float tmp[4];
  int r = blockIdx.x;
  const float* xr = x + (long)r*EN;
  float s=0.f;
  for (int j=threadIdx.x; j<EN; j+=256){ float v = xr[j]; s += v*v; }
  float t = blk_reduce(s, tmp);
  if (threadIdx.x==0) xx[r] = t*(1.0f/589824.0f);
}

// ---- KL mu^2 ----
__global__ void k_mu2(const float* __restrict__ w0, const float* __restrict__ w1,
                      const float* __restrict__ w2, const float* __restrict__ w3,
                      float* __restrict__ klacc){
  __shared__ float tmp[4];
  const float* w = (blockIdx.y==0)?w0:(blockIdx.y==1)?w1:(blockIdx.y==2)?w2:w3;
  const float4* w4 = (const float4*)w;
  float s=0.f;
  for (int i=blockIdx.x*256+threadIdx.x; i<147456; i+=gridDim.x*256){
    float4 v = w4[i];
    s += v.x*v.x + v.y*v.y + v.z*v.z + v.w*v.w;
  }
  float r = blk_reduce(s, tmp);
  if (threadIdx.x==0) atomicAdd(&klacc[0], r);
}

// ---- transpose weights to bf16 ----
__global__ void k_wt(const float* __restrict__ w0, const float* __restrict__ w1,
                     const float* __restrict__ w2, const float* __restrict__ w3,
                     u16* __restrict__ wt){
  __shared__ float t[64*65];
  const float* W = (blockIdx.z==0)?w0:(blockIdx.z==1)?w1:(blockIdx.z==2)?w2:w3;
  u16* WT = wt + (long)blockIdx.z*589824;
  int r0 = blockIdx.y<<6, c0 = blockIdx.x<<6;
  int tid = threadIdx.x;
  #pragma unroll
  for (int it=0; it<16; ++it){
    int idx=(it<<8)+tid; int r=idx>>6, c=idx&63;
    t[c*65+r] = W[(long)(r0+r)*EN + c0+c];
  }
  __syncthreads();
  #pragma unroll
  for (int it=0; it<16; ++it){
    int idx=(it<<8)+tid; int c=idx>>6, r=idx&63;
    WT[(long)(c0+c)*EN + r0+r] = f2b(t[c*65+r]);
  }
}

// ---- sq/64, sk/64 arrays ----
__global__ void k_sigarr(const float* __restrict__ xx, const float* __restrict__ wsig,
                         u16* __restrict__ sqd, u16* __restrict__ skd){
  int r = blockIdx.x;
  float xr = xx[r];
  for (int c=threadIdx.x; c<EN; c+=256){
    sqd[(long)r*EN+c] = f2b(sp_f(xr*wsig[c])*(1.0f/64.0f));
    skd[(long)r*EN+c] = f2b(sp_f(xr*wsig[EN+c])*(1.0f/64.0f));
  }
}

// ---- svT[b,h][d][k] = softplus(xx[b,k]*wsig_v[h,d]) ----
__global__ void k_svt(const float* __restrict__ xx, const float* __restrict__ wsig,
                      u16* __restrict__ svT){
  __shared__ float sxx[64], swv[64];
  int kt=blockIdx.x, h=blockIdx.y, b=blockIdx.z, tid=threadIdx.x;
  if (tid < 64){
    sxx[tid] = xx[(long)b*SN + (kt<<6) + tid];
    swv[tid] = wsig[2*EN + (h<<6) + tid];
  }
  __syncthreads();
  long obase = (((long)(b*HN+h))<<6)*SN + (kt<<6);
  #pragma unroll
  for (int it=0; it<16; ++it){
    int idx=(it<<8)+tid; int d=idx>>6, k=idx&63;
    svT[obase + (long)d*SN + k] = f2b(sp_f(sxx[k]*swv[d]));
  }
}

// ---- projections via MFMA; z=2 (v) writes transposed mvT + mv2T ----
__global__ __launch_bounds__(256)
void k_projmm(const float* __restrict__ x, const u16* __restrict__ WT,
              u16* __restrict__ oq, u16* __restrict__ ok,
              u16* __restrict__ mvT, u16* __restrict__ mv2T){
  __shared__ __align__(16) u16 lds[8192];
  u16* At = lds; u16* Bt = lds + 4096;
  const int tid = threadIdx.x;
  const int w = tid>>6, l = tid&63, l15 = l&15, g = l>>4;
  const int m0 = blockIdx.y<<6, n0 = blockIdx.x<<6;
  const u16* Wt = WT + (long)blockIdx.z*589824;
  f32x4 acc[4];
  #pragma unroll
  for (int t=0;t<4;++t){ acc[t][0]=0;acc[t][1]=0;acc[t][2]=0;acc[t][3]=0; }
  for (int k0=0; k0<EN; k0+=64){
    __syncthreads();
    #pragma unroll
    for (int it=0; it<2; ++it){
      int idx=(it<<8)+tid; int row=idx>>3, seg=idx&7;
      const float* sp = x + (long)(m0+row)*EN + k0 + (seg<<3);
      float4 a = *(const float4*)sp; float4 c = *(const float4*)(sp+4);
      bf16x8 v;
      v[0]=(short)f2b(a.x); v[1]=(short)f2b(a.y); v[2]=(short)f2b(a.z); v[3]=(short)f2b(a.w);
      v[4]=(short)f2b(c.x); v[5]=(short)f2b(c.y); v[6]=(short)f2b(c.z); v[7]=(short)f2b(c.w);
      int a16=(row<<3)+(seg^(row&7));
      *(bf16x8*)(At + (a16<<3)) = v;
    }
    stage64(Bt, Wt + (long)n0*EN + k0, EN, tid);
    __syncthreads();
    #pragma unroll
    for (int s=0;s<2;++s){
      int sg=(s<<2)+g;
      bf16x8 af = ldsr(At, (w<<4)+l15, sg);
      #pragma unroll
      for (int t=0;t<4;++t)
        acc[t] = mfma16(af, ldsr(Bt,(t<<4)+l15,sg), acc[t]);
    }
  }
  if (blockIdx.z < 2){
    u16* out = blockIdx.z ? ok : oq;
    #pragma unroll
    for (int t=0;t<4;++t){
      int col = n0 + (t<<4) + l15;
      #pragma unroll
      for (int r=0;r<4;++r){
        long row = m0 + (w<<4) + (g<<2) + r;
        out[row*EN + col] = f2b(acc[t][r]);
      }
    }
  } else {
    int b  = m0 >> 10;
    int hh = n0 >> 6;
    long obase = (((long)(b*HN+hh))<<6)*SN;
    int tok0 = (m0 & 1023) + (w<<4) + (g<<2);
    #pragma unroll
    for (int t=0;t<4;++t){
      int d = (t<<4) + l15;
      u16x4 m4, s4;
      #pragma unroll
      for (int r=0;r<4;++r){
        u16 mb = f2b(acc[t][r]);
        m4[r] = mb;
        float mf = b2f(mb);
        s4[r] = f2b(mf*mf);
      }
      *(u16x4*)&mvT[obase + (long)d*SN + tok0]  = m4;
      *(u16x4*)&mv2T[obase + (long)d*SN + tok0] = s4;
    }
  }
}

// ---- Z kernel: zinv[b,h,q] = 1/sum_k exp(mu_score/8); 512 thr, q-tile 128,
//      register prefetch, XCD-swizzled 384-block grid ----
__global__ __launch_bounds__(512)
void k_z(const u16* __restrict__ qh, const u16* __restrict__ kh,
         float* __restrict__ zi){
  __shared__ __align__(16) u16 Tk[4096];
  const int tid = threadIdx.x;
  const int w = tid>>6, l = tid&63, l15 = l&15, g = l>>4;
  const int i = blockIdx.x;
  const int xcd = i & 7, slot = i >> 3;
  const int qt = slot & 7;
  const int pair = xcd*6 + (slot >> 3);
  const int h = pair % HN, b = pair / HN;
  const int q0 = qt<<7;
  const long bS = (long)b*SN;
  bf16x8 amq[2];
  {
    long qrow = (bS + q0 + (w<<4) + l15) * EN;
    #pragma unroll
    for (int s=0;s<2;++s)
      amq[s] = *(const bf16x8*)(qh + qrow + (h<<6) + (s<<5) + (g<<3));
  }
  const u16* khb = kh + bS*EN + (h<<6);
  const int srow = tid>>3, sseg = tid&7;
  const int a16o = (((srow<<3) + (sseg ^ (srow&7)))<<3);
  bf16x8 pf = *(const bf16x8*)(khb + (long)srow*EN + (sseg<<3));
  f32x4 zacc = {0.f,0.f,0.f,0.f};
  for (int kt=0; kt<16; ++kt){
    __syncthreads();
    *(bf16x8*)(Tk + a16o) = pf;
    __syncthreads();
    if (kt < 15)
      pf = *(const bf16x8*)(khb + (long)(((kt+1)<<6)+srow)*EN + (sseg<<3));
    f32x4 smu[4];
    #pragma unroll
    for (int t=0;t<4;++t){ smu[t][0]=0;smu[t][1]=0;smu[t][2]=0;smu[t][3]=0; }
    #pragma unroll
    for (int s=0;s<2;++s){
      int sg=(s<<2)+g;
      #pragma unroll
      for (int t=0;t<4;++t)
        smu[t] = mfma16(amq[s], ldsr(Tk,(t<<4)+l15,sg), smu[t]);
    }
    #pragma unroll
    for (int t=0;t<4;++t)
      #pragma unroll
      for (int r=0;r<4;++r)
        zacc[r] += __expf(smu[t][r]*0.125f);
  }
  #pragma unroll
  for (int m=1; m<16; m<<=1){
    #pragma unroll
    for (int r=0;r<4;++r) zacc[r] += __shfl_xor(zacc[r], m, 64);
  }
  if (l15 == 0){
    long zbase = (((long)(b*HN+h))<<10) + q0 + (w<<4) + (g<<2);
    #pragma unroll
    for (int r=0;r<4;++r) zi[zbase + r] = 1.0f/zacc[r];
  }
}

// ---- single-pass fused Bayesian attention; 8 waves, q-tile 128, 80KB LDS,
//      async register prefetch of next k-tile, packed u32 P tile ----
__global__ __launch_bounds__(512, 2)
void k_attn(const u16* __restrict__ qh, const u16* __restrict__ kh,
            const u16* __restrict__ sqd, const u16* __restrict__ skd,
            const u16* __restrict__ mvT, const u16* __restrict__ svT,
            const u16* __restrict__ mv2T, const float* __restrict__ zi,
            u16* __restrict__ muh, u16* __restrict__ sgh){
  extern __shared__ u16 lds2[];
  u16* Tk  = lds2;
  u16* Tsk = lds2 + 4096;
  u16* Tsq = lds2 + 8192;
  u16* Tmv = lds2 + 12288;
  u16* Tsv = lds2 + 16384;
  u16* Tm2 = lds2 + 20480;
  const int tid = threadIdx.x;
  const int w = tid>>6, l = tid&63, l15 = l&15, g = l>>4;
  unsigned* Pu = (unsigned*)(lds2 + 24576) + (w<<10);   // [16][64] u32, 4KB/wave
  // XCD swizzle: 384 blocks = 8 XCDs x 6 (b,h) pairs x 8 q-tiles
  const int i = blockIdx.x;
  const int xcd = i & 7, slot = i >> 3;
  const int qt = slot & 7;
  const int pair = xcd*6 + (slot >> 3);
  const int h = pair % HN, b = pair / HN;
  const int q0 = qt<<7;
  const long bS = (long)b*SN;

  // constant A-fragments (wave's 16 q-rows)
  bf16x8 amq[2], acb[2], amk2[2];
  {
    long qrow = (bS + q0 + (w<<4) + l15) * EN;
    #pragma unroll
    for (int s=0;s<2;++s){
      int eoff = (h<<6) + (s<<5) + (g<<3);
      bf16x8 q8 = *(const bf16x8*)(qh + qrow + eoff);
      bf16x8 k8 = *(const bf16x8*)(kh + qrow + eoff);
      bf16x8 s8 = *(const bf16x8*)(sqd + qrow + eoff);
      amq[s] = q8;
      bf16x8 t2, tc;
      #pragma unroll
      for (int j=0;j<8;++j){
        float kv = b2f((u16)k8[j]);
        t2[j] = (short)f2b(kv*kv);
        float qv = b2f((u16)q8[j]);
        float sv = b2f((u16)s8[j]) * 64.0f;
        tc[j] = (short)f2b(qv*qv + sv);
      }
      amk2[s] = t2; acb[s] = tc;
    }
  }
  float zl[4];
  {
    long zbase = (((long)(b*HN+h))<<10) + q0 + (w<<4) + (g<<2);
    #pragma unroll
    for (int r=0;r<4;++r) zl[r] = zi[zbase + r];
  }

  const u16* khb = kh  + bS*EN + (h<<6);
  const u16* skb = skd + bS*EN + (h<<6);
  const u16* sqb = sqd + bS*EN + (h<<6);
  const long hb64 = ((long)(b*HN+h))<<6;
  const u16* mvb = mvT  + hb64*SN;
  const u16* svb = svT  + hb64*SN;
  const u16* m2b = mv2T + hb64*SN;

  f32x4 accM[4], acc2[4], acc3[4];
  #pragma unroll
  for (int t=0;t<4;++t){
    accM[t][0]=0;accM[t][1]=0;accM[t][2]=0;accM[t][3]=0;
    acc2[t][0]=0;acc2[t][1]=0;acc2[t][2]=0;acc2[t][3]=0;
    acc3[t][0]=0;acc3[t][1]=0;acc3[t][2]=0;acc3[t][3]=0;
  }

  const int srow = tid>>3, sseg = tid&7;
  const int a16o = (((srow<<3) + (sseg ^ (srow&7)))<<3);

  // prefetch k-tile 0 into registers
  bf16x8 pf0, pf1, pf2, pf3, pf4, pf5;
  {
    long off1 = (long)srow*EN + (sseg<<3);
    long off2 = (long)srow*SN + (sseg<<3);
    pf0 = *(const bf16x8*)(khb+off1);
    pf1 = *(const bf16x8*)(skb+off1);
    pf2 = *(const bf16x8*)(sqb+off1);
    pf3 = *(const bf16x8*)(mvb+off2);
    pf4 = *(const bf16x8*)(svb+off2);
    pf5 = *(const bf16x8*)(m2b+off2);
  }

  for (int kt=0; kt<16; ++kt){
    __syncthreads();                      // prior compute done reading LDS
    *(bf16x8*)(Tk +a16o) = pf0;
    *(bf16x8*)(Tsk+a16o) = pf1;
    *(bf16x8*)(Tsq+a16o) = pf2;
    *(bf16x8*)(Tmv+a16o) = pf3;
    *(bf16x8*)(Tsv+a16o) = pf4;
    *(bf16x8*)(Tm2+a16o) = pf5;
    __syncthreads();                      // tiles visible
    if (kt < 15){                         // issue next-tile loads; latency
      long off1 = (long)(((kt+1)<<6)+srow)*EN + (sseg<<3);   // hides under
      long off2 = (long)srow*SN + ((kt+1)<<6) + (sseg<<3);   // score+PV
      pf0 = *(const bf16x8*)(khb+off1);
      pf1 = *(const bf16x8*)(skb+off1);
      pf2 = *(const bf16x8*)(sqb+off1);
      pf3 = *(const bf16x8*)(mvb+off2);
      pf4 = *(const bf16x8*)(svb+off2);
      pf5 = *(const bf16x8*)(m2b+off2);
    }

    // score phase, serialized over t (keeps live smu/ssg at 8 VGPRs)
    #pragma unroll
    for (int t=0;t<4;++t){
      f32x4 smu = {0.f,0.f,0.f,0.f}, ssg = {0.f,0.f,0.f,0.f};
      #pragma unroll
      for (int s=0;s<2;++s){
        int sg=(s<<2)+g;
        int rn = (t<<4)+l15;
        smu = mfma16(amq[s],  ldsr(Tk, rn,sg), smu);
        ssg = mfma16(acb[s],  ldsr(Tsk,rn,sg), ssg);
        ssg = mfma16(amk2[s], ldsr(Tsq,rn,sg), ssg);
      }
      #pragma unroll
      for (int r=0;r<4;++r){
        float e  = __expf(smu[r]*0.125f);
        float wv = e*zl[r];
        float u  = wv - wv*wv;
        float sw = u*u*ssg[r]*(1.0f/65536.0f);
        int prow = (g<<2)+r, pcol = (t<<4)+l15;
        int a32 = (((prow<<3) + ((pcol>>3)^(prow&7)))<<3) + (pcol&7);
        Pu[a32] = cvtpk(wv, sw);          // lo=bf16(w), hi=bf16(Sw)
      }
    }
    asm volatile("s_waitcnt lgkmcnt(0)" ::: "memory");
    #pragma unroll
    for (int s=0;s<2;++s){
      int sg=(s<<2)+g;
      const u32x4* pp = (const u32x4*)(Pu + (((l15<<3) + (sg ^ (l15&7)))<<3));
      u32x4 pA = pp[0], pB = pp[1];
      unsigned qa[8] = {pA[0],pA[1],pA[2],pA[3],pB[0],pB[1],pB[2],pB[3]};
      u32x4 awu, agu, pau;
      #pragma unroll
      for (int i2=0;i2<4;++i2){
        unsigned lo = qa[2*i2], hi = qa[2*i2+1];
        awu[i2] = (lo & 0xffffu) | (hi << 16);
        agu[i2] = (lo >> 16) | (hi & 0xffff0000u);
        float w0 = __uint_as_float(lo<<16), g0 = __uint_as_float(lo & 0xffff0000u);
        float w1 = __uint_as_float(hi<<16), g1 = __uint_as_float(hi & 0xffff0000u);
        pau[i2] = cvtpk(fmaf(w0,w0,g0), fmaf(w1,w1,g1));   // w^2 + Sw
      }
      bf16x8 aw = u2b(awu), ag = u2b(agu), pa = u2b(pau);
      #pragma unroll
      for (int t=0;t<4;++t){
        int rn = (t<<4)+l15;
        accM[t] = mfma16(aw, ldsr(Tmv,rn,sg), accM[t]);
        acc2[t] = mfma16(pa, ldsr(Tsv,rn,sg), acc2[t]);
        acc3[t] = mfma16(ag, ldsr(Tm2,rn,sg), acc3[t]);
      }
    }
  }
  long grow0 = bS + q0 + (w<<4) + (g<<2);
  #pragma unroll
  for (int t=0;t<4;++t){
    int col = (h<<6) + (t<<4) + l15;
    #pragma unroll
    for (int r=0;r<4;++r){
      long o = (grow0 + r)*EN + col;
      muh[o] = f2b(accM[t][r]);
      sgh[o] = f2b(sp_f((acc2[t][r]+acc3[t][r])*(1.0f/1024.0f)));
    }
  }
}

// ---- per-row combined scalar ----
__global__ void k_rows(const u16* __restrict__ muh, const u16* __restrict__ sgh,
                       float* __restrict__ rcomb){
  __shared__ float tmp[4];
  int r = blockIdx.x;
  const u16* m = muh + (long)r*EN;
  const u16* s = sgh + (long)r*EN;
  float s1=0.f, s2=0.f;
  for (int j=threadIdx.x; j<EN; j+=256){ float a=b2f(m[j]); s1+=a*a; s2+=b2f(s[j]); }
  float r1 = blk_reduce(s1, tmp);
  float r2 = blk_reduce(s2, tmp);
  if (threadIdx.x==0) rcomb[r] = r1*(1.0f/589824.0f) + r2*(1.0f/768.0f);
}

// ---- output linear with fused Sigma epilogue ----
__global__ __launch_bounds__(256)
void k_outmm(const u16* __restrict__ muh, const u16* __restrict__ sgh,
             const u16* __restrict__ WTo, const float* __restrict__ rcomb,
             const float* __restrict__ wso, float* __restrict__ mu_out,
             float* __restrict__ sg_out){
  __shared__ __align__(16) u16 lds[12288];
  u16* Am = lds; u16* As = lds + 4096; u16* Bt = lds + 8192;
  const int tid = threadIdx.x;
  const int w = tid>>6, l = tid&63, l15 = l&15, g = l>>4;
  const int m0 = blockIdx.y<<6, n0 = blockIdx.x<<6;
  f32x4 accM[4], accS[4];
  #pragma unroll
  for (int t=0;t<4;++t){
    accM[t][0]=0;accM[t][1]=0;accM[t][2]=0;accM[t][3]=0;
    accS[t][0]=0;accS[t][1]=0;accS[t][2]=0;accS[t][3]=0;
  }
  for (int k0=0; k0<EN; k0+=64){
    __syncthreads();
    stage64(Am, muh + (long)m0*EN + k0, EN, tid);
    stage64(As, sgh + (long)m0*EN + k0, EN, tid);
    stage64(Bt, WTo + (long)n0*EN + k0, EN, tid);
    __syncthreads();
    #pragma unroll
    for (int s=0;s<2;++s){
      int sg=(s<<2)+g;
      bf16x8 am = ldsr(Am, (w<<4)+l15, sg);
      bf16x8 as = ldsr(As, (w<<4)+l15, sg);
      #pragma unroll
      for (int t=0;t<4;++t){
        bf16x8 bw = ldsr(Bt,(t<<4)+l15,sg);
        accM[t] = mfma16(am, bw, accM[t]);
        accS[t] = mfma16(as, sq8(bw), accS[t]);
      }
    }
  }
  float rc4[4];
  #pragma unroll
  for (int r=0;r<4;++r) rc4[r] = rcomb[m0 + (w<<4) + (g<<2) + r];
  #pragma unroll
  for (int t=0;t<4;++t){
    int col = n0 + (t<<4) + l15;
    float wsc = wso[col];
    #pragma unroll
    for (int r=0;r<4;++r){
      long row = m0 + (w<<4) + (g<<2) + r;
      mu_out[row*EN + col] = accM[t][r];
      float spre = accS[t][r]*(1.0f/768.0f) + rc4[r]*wsc;
      sg_out[row*EN + col] = sp_f(sp_f(spre));
    }
  }
}

// ---- KL finalize ----
__global__ void k_klf(const float* __restrict__ klacc, float* __restrict__ out){
  float Smu2 = klacc[0], Ssig = klacc[1], Ssp = klacc[2];
  const float C = -5.60517018599f;
  out[0] = 0.5f*(4.f*C - Ssig*(1.0f/768.0f) + Ssp*(1.0f/7.68f) + Smu2*(1.0f/5898.24f));
}

extern "C" void kernel_launch(void* const* d_in, const int* in_sizes, int n_in,
                              void* d_out, int out_size, void* d_ws, size_t ws_size,
                              hipStream_t stream) {
  (void)in_sizes; (void)n_in; (void)out_size; (void)ws_size;
  const float* x      = (const float*)d_in[0];
  const float* wq_mu  = (const float*)d_in[1];
  const float* wq_sig = (const float*)d_in[2];
  const float* wk_mu  = (const float*)d_in[3];
  const float* wk_sig = (const float*)d_in[4];
  const float* wv_mu  = (const float*)d_in[5];
  const float* wv_sig = (const float*)d_in[6];
  const float* wo_mu  = (const float*)d_in[7];
  const float* wo_sig = (const float*)d_in[8];

  char* wsb = (char*)d_ws;
  float* xx    = (float*)(wsb + OFF_XX);
  float* rc    = (float*)(wsb + OFF_RC);
  float* wsig  = (float*)(wsb + OFF_WSIG);
  float* kla   = (float*)(wsb + OFF_KL);
  float* zi    = (float*)(wsb + OFF_ZI);
  u16*   WT    = (u16*)(wsb + OFF_WT);
  u16*   qh    = (u16*)(wsb + OFF_QH);
  u16*   kh    = (u16*)(wsb + OFF_KH);
  u16*   sqd   = (u16*)(wsb + OFF_SQD);
  u16*   skd   = (u16*)(wsb + OFF_SKD);
  u16*   mvT   = (u16*)(wsb + OFF_MVT);
  u16*   mv2T  = (u16*)(wsb + OFF_MV2);
  u16*   svT   = (u16*)(wsb + OFF_SVT);
  u16*   muh   = (u16*)(wsb + OFF_MUH);
  u16*   sgh   = (u16*)(wsb + OFF_SGH);

  float* mu_out = (float*)d_out;
  float* sg_out = mu_out + BSE;
  float* kl_out = mu_out + 2*BSE;

  (void)hipMemsetAsync(kla, 0, 3*sizeof(float), stream);
  k_prep<<<4, 256, 0, stream>>>(wq_sig, wk_sig, wv_sig, wo_sig, wsig, kla);
  k_xx<<<BSN, 256, 0, stream>>>(x, xx);
  k_mu2<<<dim3(64,4), 256, 0, stream>>>(wq_mu, wk_mu, wv_mu, wo_mu, kla);
  k_wt<<<dim3(12,12,4), 256, 0, stream>>>(wq_mu, wk_mu, wv_mu, wo_mu, WT);
  k_sigarr<<<BSN, 256, 0, stream>>>(xx, wsig, sqd, skd);
  k_svt<<<dim3(16,HN,4), 256, 0, stream>>>(xx, wsig, svT);
  k_projmm<<<dim3(12,64,3), 256, 0, stream>>>(x, WT, qh, kh, mvT, mv2T);
  k_z<<<384, 512, 0, stream>>>(qh, kh, zi);

  const int attn_lds = 40960*2;
  (void)hipFuncSetAttribute((const void*)k_attn,
                      hipFuncAttributeMaxDynamicSharedMemorySize, attn_lds);
  k_attn<<<384, 512, attn_lds, stream>>>(qh, kh, sqd, skd, mvT, svT,
                                         mv2T, zi, muh, sgh);
  k_rows<<<BSN, 256, 0, stream>>>(muh, sgh, rc);
  k_outmm<<<dim3(12,64), 256, 0, stream>>>(muh, sgh, WT + 3l*589824, rc,
                                           wsig + 3*EN, mu_out, sg_out);
  k_klf<<<1, 1, 0, stream>>>(kla, kl_out);
}

// Round 7
// 341.588 us; speedup vs baseline: 7.0814x; 1.0516x over previous
//
#include <hip/hip_runtime.h>
#include <math.h>

#define EN 768
#define SN 1024
#define HN 12
#define BSN 4096
#define BSE 3145728

#define AS1 __attribute__((address_space(1)))
#define AS3 __attribute__((address_space(3)))

typedef __attribute__((ext_vector_type(8))) short bf16x8;
typedef __attribute__((ext_vector_type(4))) float f32x4;
typedef __attribute__((ext_vector_type(4))) unsigned short u16x4;
typedef __attribute__((ext_vector_type(4))) unsigned int u32x4;
typedef unsigned short u16;

// ---- workspace byte offsets (~59.9 MB) ----
#define OFF_XX   0u
#define OFF_RC   16384u
#define OFF_WSIG 32768u
#define OFF_KL   45056u
#define OFF_ZI   49152u       // [4*12*1024] f32 zinv
#define OFF_WT   262144u      // 4 * 768*768 u16
#define OFF_QH   4980736u
#define OFF_KH   11272192u
#define OFF_SQD  17563648u
#define OFF_SKD  23855104u
#define OFF_MVT  30146560u
#define OFF_MV2  36438016u
#define OFF_SVT  42729472u
#define OFF_MUH  49020928u
#define OFF_SGH  55312384u
#define OFF_WT2  61603840u    // 768*768 u16 (wo^2 bf16)

__device__ __forceinline__ float sp_f(float x){
  return fmaxf(x, 0.f) + log1pf(__expf(-fabsf(x)));
}
__device__ __forceinline__ u16 f2b(float f){
  unsigned u = __float_as_uint(f);
  return (u16)((u + 0x7fffu + ((u>>16)&1u)) >> 16);
}
__device__ __forceinline__ float b2f(u16 h){
  return __uint_as_float(((unsigned)h)<<16);
}
// packed f32x2 -> bf16x2 in one instruction (RNE, same bits as f2b)
__device__ __forceinline__ unsigned cvtpk(float lo, float hi){
  unsigned r;
  asm("v_cvt_pk_bf16_f32 %0, %1, %2" : "=v"(r) : "v"(lo), "v"(hi));
  return r;
}
__device__ __forceinline__ bf16x8 u2b(u32x4 v){
  union{u32x4 u; bf16x8 b;} x; x.u = v; return x.b;
}
__device__ __forceinline__ f32x4 mfma16(bf16x8 a, bf16x8 b, f32x4 c){
  return __builtin_amdgcn_mfma_f32_16x16x32_bf16(a, b, c, 0, 0, 0);
}
// LDS frag read from swizzled [rows][64] bf16 tile
__device__ __forceinline__ bf16x8 ldsr(const u16* t, int row, int sg){
  int a16 = (row<<3) + (sg ^ (row&7));
  return *(const bf16x8*)(t + (a16<<3));
}
// stage 64x64 bf16 tile with 256 threads (2 slots/thread) via registers
__device__ __forceinline__ void stage64(u16* dst, const u16* src, int rstride, int tid){
  #pragma unroll
  for (int it=0; it<2; ++it){
    int idx = (it<<8) + tid;
    int row = idx>>3, seg = idx&7;
    bf16x8 v = *(const bf16x8*)(src + (long)row*rstride + (seg<<3));
    int a16 = (row<<3) + (seg ^ (row&7));
    *(bf16x8*)(dst + (a16<<3)) = v;
  }
}
// stage 64x64 bf16 tile via global_load_lds (4 waves, 2 issues/wave).
// LDS dest is linear (wave-uniform base + lane*16B); the XOR swizzle is
// achieved by permuting the per-lane GLOBAL source segment (m173 pattern).
__device__ __forceinline__ void gstage(u16* ltile, const u16* gsrc, long rstride,
                                       int w, int l){
  #pragma unroll
  for (int i=0;i<2;++i){
    int slot = (i<<8) + (w<<6) + l;          // linear 16B slot 0..511
    int row  = slot >> 3;
    int seg  = (slot & 7) ^ (row & 7);       // swizzled source segment
    const u16* g = gsrc + (long)row*rstride + (seg<<3);
    u16* d = ltile + (((i<<8) + (w<<6))<<3); // wave-uniform base
    __builtin_amdgcn_global_load_lds((AS1 void*)g, (AS3 void*)d, 16, 0, 0);
  }
}

__device__ __forceinline__ float blk_reduce(float v, float* tmp){
  #pragma unroll
  for (int off = 32; off; off >>= 1) v += __shfl_down(v, off, 64);
  int w = threadIdx.x >> 6;
  if ((threadIdx.x & 63) == 0) tmp[w] = v;
  __syncthreads();
  float r = 0.f;
  if (threadIdx.x == 0) r = tmp[0] + tmp[1] + tmp[2] + tmp[3];
  __syncthreads();
  return r;
}

// ---- softplus(w_sigma) + KL sigma terms ----
__global__ void k_prep(const float* __restrict__ s0, const float* __restrict__ s1,
                       const float* __restrict__ s2, const float* __restrict__ s3,
                       float* __restrict__ wsig, float* __restrict__ klacc){
  __shared__ float tmp[4];
  const float* src = (blockIdx.x==0)?s0:(blockIdx.x==1)?s1:(blockIdx.x==2)?s2:s3;
  int l = blockIdx.x;
  float ssum=0.f, spsum=0.f;
  for (int j=threadIdx.x; j<EN; j+=256){
    float sg = src[j];
    float w  = log1pf(__expf(sg));
    wsig[l*EN+j] = w;
    ssum += sg; spsum += w;
  }
  float a = blk_reduce(ssum, tmp);
  float b = blk_reduce(spsum, tmp);
  if (threadIdx.x==0){ atomicAdd(&klacc[1], a); atomicAdd(&klacc[2], b); }
}

// ---- xx[r] = sum_e (x/768)^2 ----
__global__ void k_xx(const float* __restrict__ x, float* __restrict__ xx){
  __shared__ float tmp[4];
  int r = blockIdx.x;
  const float* xr = x + (long)r*EN;
  float s=0.f;
  for (int j=threadIdx.x; j<EN; j+=256){ float v = xr[j]; s += v*v; }
  float t = blk_reduce(s, tmp);
  if (threadIdx.x==0) xx[r] = t*(1.0f/589824.0f);
}

// ---- KL mu^2 ----
__global__ void k_mu2(const float* __restrict__ w0, const float* __restrict__ w1,
                      const float* __restrict__ w2, const float* __restrict__ w3,
                      float* __restrict__ klacc){
  __shared__ float tmp[4];
  const float* w = (blockIdx.y==0)?w0:(blockIdx.y==1)?w1:(blockIdx.y==2)?w2:w3;
  const float4* w4 = (const float4*)w;
  float s=0.f;
  for (int i=blockIdx.x*256+threadIdx.x; i<147456; i+=gridDim.x*256){
    float4 v = w4[i];
    s += v.x*v.x + v.y*v.y + v.z*v.z + v.w*v.w;
  }
  float r = blk_reduce(s, tmp);
  if (threadIdx.x==0) atomicAdd(&klacc[0], r);
}

// ---- transpose weights to bf16; z=3 also writes wo^2 (bf16) ----
__global__ void k_wt(const float* __restrict__ w0, const float* __restrict__ w1,
                     const float* __restrict__ w2, const float* __restrict__ w3,
                     u16* __restrict__ wt, u16* __restrict__ wt2){
  __shared__ float t[64*65];
  const float* W = (blockIdx.z==0)?w0:(blockIdx.z==1)?w1:(blockIdx.z==2)?w2:w3;
  u16* WT = wt + (long)blockIdx.z*589824;
  int r0 = blockIdx.y<<6, c0 = blockIdx.x<<6;
  int tid = threadIdx.x;
  #pragma unroll
  for (int it=0; it<16; ++it){
    int idx=(it<<8)+tid; int r=idx>>6, c=idx&63;
    t[c*65+r] = W[(long)(r0+r)*EN + c0+c];
  }
  __syncthreads();
  #pragma unroll
  for (int it=0; it<16; ++it){
    int idx=(it<<8)+tid; int c=idx>>6, r=idx&63;
    u16 bb = f2b(t[c*65+r]);
    WT[(long)(c0+c)*EN + r0+r] = bb;
    if (blockIdx.z == 3){
      float bf = b2f(bb);
      wt2[(long)(c0+c)*EN + r0+r] = f2b(bf*bf);
    }
  }
}

// ---- sq/64, sk/64 arrays ----
__global__ void k_sigarr(const float* __restrict__ xx, const float* __restrict__ wsig,
                         u16* __restrict__ sqd, u16* __restrict__ skd){
  int r = blockIdx.x;
  float xr = xx[r];
  for (int c=threadIdx.x; c<EN; c+=256){
    sqd[(long)r*EN+c] = f2b(sp_f(xr*wsig[c])*(1.0f/64.0f));
    skd[(long)r*EN+c] = f2b(sp_f(xr*wsig[EN+c])*(1.0f/64.0f));
  }
}

// ---- svT[b,h][d][k] = softplus(xx[b,k]*wsig_v[h,d]) ----
__global__ void k_svt(const float* __restrict__ xx, const float* __restrict__ wsig,
                      u16* __restrict__ svT){
  __shared__ float sxx[64], swv[64];
  int kt=blockIdx.x, h=blockIdx.y, b=blockIdx.z, tid=threadIdx.x;
  if (tid < 64){
    sxx[tid] = xx[(long)b*SN + (kt<<6) + tid];
    swv[tid] = wsig[2*EN + (h<<6) + tid];
  }
  __syncthreads();
  long obase = (((long)(b*HN+h))<<6)*SN + (kt<<6);
  #pragma unroll
  for (int it=0; it<16; ++it){
    int idx=(it<<8)+tid; int d=idx>>6, k=idx&63;
    svT[obase + (long)d*SN + k] = f2b(sp_f(sxx[k]*swv[d]));
  }
}

// ---- projections via MFMA; z=2 (v) writes transposed mvT + mv2T ----
__global__ __launch_bounds__(256)
void k_projmm(const float* __restrict__ x, const u16* __restrict__ WT,
              u16* __restrict__ oq, u16* __restrict__ ok,
              u16* __restrict__ mvT, u16* __restrict__ mv2T){
  __shared__ __align__(16) u16 lds[8192];
  u16* At = lds; u16* Bt = lds + 4096;
  const int tid = threadIdx.x;
  const int w = tid>>6, l = tid&63, l15 = l&15, g = l>>4;
  const int m0 = blockIdx.y<<6, n0 = blockIdx.x<<6;
  const u16* Wt = WT + (long)blockIdx.z*589824;
  f32x4 acc[4];
  #pragma unroll
  for (int t=0;t<4;++t){ acc[t][0]=0;acc[t][1]=0;acc[t][2]=0;acc[t][3]=0; }
  for (int k0=0; k0<EN; k0+=64){
    __syncthreads();
    #pragma unroll
    for (int it=0; it<2; ++it){
      int idx=(it<<8)+tid; int row=idx>>3, seg=idx&7;
      const float* sp = x + (long)(m0+row)*EN + k0 + (seg<<3);
      float4 a = *(const float4*)sp; float4 c = *(const float4*)(sp+4);
      bf16x8 v;
      v[0]=(short)f2b(a.x); v[1]=(short)f2b(a.y); v[2]=(short)f2b(a.z); v[3]=(short)f2b(a.w);
      v[4]=(short)f2b(c.x); v[5]=(short)f2b(c.y); v[6]=(short)f2b(c.z); v[7]=(short)f2b(c.w);
      int a16=(row<<3)+(seg^(row&7));
      *(bf16x8*)(At + (a16<<3)) = v;
    }
    stage64(Bt, Wt + (long)n0*EN + k0, EN, tid);
    __syncthreads();
    #pragma unroll
    for (int s=0;s<2;++s){
      int sg=(s<<2)+g;
      bf16x8 af = ldsr(At, (w<<4)+l15, sg);
      #pragma unroll
      for (int t=0;t<4;++t)
        acc[t] = mfma16(af, ldsr(Bt,(t<<4)+l15,sg), acc[t]);
    }
  }
  if (blockIdx.z < 2){
    u16* out = blockIdx.z ? ok : oq;
    #pragma unroll
    for (int t=0;t<4;++t){
      int col = n0 + (t<<4) + l15;
      #pragma unroll
      for (int r=0;r<4;++r){
        long row = m0 + (w<<4) + (g<<2) + r;
        out[row*EN + col] = f2b(acc[t][r]);
      }
    }
  } else {
    int b  = m0 >> 10;
    int hh = n0 >> 6;
    long obase = (((long)(b*HN+hh))<<6)*SN;
    int tok0 = (m0 & 1023) + (w<<4) + (g<<2);
    #pragma unroll
    for (int t=0;t<4;++t){
      int d = (t<<4) + l15;
      u16x4 m4, s4;
      #pragma unroll
      for (int r=0;r<4;++r){
        u16 mb = f2b(acc[t][r]);
        m4[r] = mb;
        float mf = b2f(mb);
        s4[r] = f2b(mf*mf);
      }
      *(u16x4*)&mvT[obase + (long)d*SN + tok0]  = m4;
      *(u16x4*)&mv2T[obase + (long)d*SN + tok0] = s4;
    }
  }
}

// ---- Z kernel: zinv[b,h,q] = 1/sum_k exp(mu_score/8); 512 thr, q-tile 128,
//      register prefetch, XCD-swizzled 384-block grid ----
__global__ __launch_bounds__(512)
void k_z(const u16* __restrict__ qh, const u16* __restrict__ kh,
         float* __restrict__ zi){
  __shared__ __align__(16) u16 Tk[4096];
  const int tid = threadIdx.x;
  const int w = tid>>6, l = tid&63, l15 = l&15, g = l>>4;
  const int i = blockIdx.x;
  const int xcd = i & 7, slot = i >> 3;
  const int qt = slot & 7;
  const int pair = xcd*6 + (slot >> 3);
  const int h = pair % HN, b = pair / HN;
  const int q0 = qt<<7;
  const long bS = (long)b*SN;
  bf16x8 amq[2];
  {
    long qrow = (bS + q0 + (w<<4) + l15) * EN;
    #pragma unroll
    for (int s=0;s<2;++s)
      amq[s] = *(const bf16x8*)(qh + qrow + (h<<6) + (s<<5) + (g<<3));
  }
  const u16* khb = kh + bS*EN + (h<<6);
  const int srow = tid>>3, sseg = tid&7;
  const int a16o = (((srow<<3) + (sseg ^ (srow&7)))<<3);
  bf16x8 pf = *(const bf16x8*)(khb + (long)srow*EN + (sseg<<3));
  f32x4 zacc = {0.f,0.f,0.f,0.f};
  for (int kt=0; kt<16; ++kt){
    __syncthreads();
    *(bf16x8*)(Tk + a16o) = pf;
    __syncthreads();
    if (kt < 15)
      pf = *(const bf16x8*)(khb + (long)(((kt+1)<<6)+srow)*EN + (sseg<<3));
    f32x4 smu[4];
    #pragma unroll
    for (int t=0;t<4;++t){ smu[t][0]=0;smu[t][1]=0;smu[t][2]=0;smu[t][3]=0; }
    #pragma unroll
    for (int s=0;s<2;++s){
      int sg=(s<<2)+g;
      #pragma unroll
      for (int t=0;t<4;++t)
        smu[t] = mfma16(amq[s], ldsr(Tk,(t<<4)+l15,sg), smu[t]);
    }
    #pragma unroll
    for (int t=0;t<4;++t)
      #pragma unroll
      for (int r=0;r<4;++r)
        zacc[r] += __expf(smu[t][r]*0.125f);
  }
  #pragma unroll
  for (int m=1; m<16; m<<=1){
    #pragma unroll
    for (int r=0;r<4;++r) zacc[r] += __shfl_xor(zacc[r], m, 64);
  }
  if (l15 == 0){
    long zbase = (((long)(b*HN+h))<<10) + q0 + (w<<4) + (g<<2);
    #pragma unroll
    for (int r=0;r<4;++r) zi[zbase + r] = 1.0f/zacc[r];
  }
}

// ---- single-pass fused Bayesian attention; 4 waves, M=32/wave, q-tile 128,
//      80KB LDS, global_load_lds split-phase pipeline ----
__global__ __launch_bounds__(256, 2)
void k_attn(const u16* __restrict__ qh, const u16* __restrict__ kh,
            const u16* __restrict__ sqd, const u16* __restrict__ skd,
            const u16* __restrict__ mvT, const u16* __restrict__ svT,
            const u16* __restrict__ mv2T, const float* __restrict__ zi,
            u16* __restrict__ muh, u16* __restrict__ sgh){
  extern __shared__ u16 lds2[];
  u16* Tk  = lds2;
  u16* Tsk = lds2 + 4096;
  u16* Tsq = lds2 + 8192;
  u16* Tmv = lds2 + 12288;
  u16* Tsv = lds2 + 16384;
  u16* Tm2 = lds2 + 20480;
  const int tid = threadIdx.x;
  const int w = tid>>6, l = tid&63, l15 = l&15, g = l>>4;
  unsigned* Pu = (unsigned*)(lds2 + 24576) + (w<<11);   // 8KB/wave, 2 strips
  // XCD swizzle: 384 blocks = 8 XCDs x 6 (b,h) pairs x 8 q-tiles
  const int ib = blockIdx.x;
  const int xcd = ib & 7, slot = ib >> 3;
  const int qt = slot & 7;
  const int pair = xcd*6 + (slot >> 3);
  const int h = pair % HN, b = pair / HN;
  const int q0 = qt<<7;
  const long bS = (long)b*SN;

  // constant A-fragments: 2 strips of 16 q-rows per wave (M=32)
  bf16x8 amq[2][2], acb[2][2], amk2[2][2];
  #pragma unroll
  for (int p=0;p<2;++p){
    long qrow = (bS + q0 + (w<<5) + (p<<4) + l15) * EN;
    #pragma unroll
    for (int s=0;s<2;++s){
      int eoff = (h<<6) + (s<<5) + (g<<3);
      bf16x8 q8 = *(const bf16x8*)(qh + qrow + eoff);
      bf16x8 k8 = *(const bf16x8*)(kh + qrow + eoff);
      bf16x8 s8 = *(const bf16x8*)(sqd + qrow + eoff);
      amq[p][s] = q8;
      bf16x8 t2, tc;
      #pragma unroll
      for (int j=0;j<8;++j){
        float kv = b2f((u16)k8[j]);
        t2[j] = (short)f2b(kv*kv);
        float qv = b2f((u16)q8[j]);
        float sv = b2f((u16)s8[j]) * 64.0f;
        tc[j] = (short)f2b(qv*qv + sv);
      }
      amk2[p][s] = t2; acb[p][s] = tc;
    }
  }
  f32x4 zl[2];
  #pragma unroll
  for (int p=0;p<2;++p){
    long zbase = (((long)(b*HN+h))<<10) + q0 + (w<<5) + (p<<4) + (g<<2);
    #pragma unroll
    for (int r=0;r<4;++r) zl[p][r] = zi[zbase + r];
  }

  const u16* khb = kh  + bS*EN + (h<<6);
  const u16* skb = skd + bS*EN + (h<<6);
  const u16* sqb = sqd + bS*EN + (h<<6);
  const long hb64 = ((long)(b*HN+h))<<6;
  const u16* mvb = mvT  + hb64*SN;
  const u16* svb = svT  + hb64*SN;
  const u16* m2b = mv2T + hb64*SN;

  f32x4 accM[2][4], acc2[2][4], acc3[2][4];
  #pragma unroll
  for (int p=0;p<2;++p)
    #pragma unroll
    for (int t=0;t<4;++t){
      accM[p][t][0]=0;accM[p][t][1]=0;accM[p][t][2]=0;accM[p][t][3]=0;
      acc2[p][t][0]=0;acc2[p][t][1]=0;acc2[p][t][2]=0;acc2[p][t][3]=0;
      acc3[p][t][0]=0;acc3[p][t][1]=0;acc3[p][t][2]=0;acc3[p][t][3]=0;
    }

  // prologue: stage score tiles for kt=0
  gstage(Tk,  khb, EN, w, l);
  gstage(Tsk, skb, EN, w, l);
  gstage(Tsq, sqb, EN, w, l);

  for (int kt=0; kt<16; ++kt){
    __syncthreads();                       // score tiles ready; prev PV reads done
    gstage(Tmv, mvb + (kt<<6), SN, w, l);  // PV-tile loads fly during score phase
    gstage(Tsv, svb + (kt<<6), SN, w, l);
    gstage(Tm2, m2b + (kt<<6), SN, w, l);

    // ---- score phase: each B-frag read feeds both strips ----
    #pragma unroll
    for (int t=0;t<4;++t){
      f32x4 smu[2], ssg[2];
      #pragma unroll
      for (int p=0;p<2;++p){
        smu[p][0]=0;smu[p][1]=0;smu[p][2]=0;smu[p][3]=0;
        ssg[p][0]=0;ssg[p][1]=0;ssg[p][2]=0;ssg[p][3]=0;
      }
      int rn = (t<<4)+l15;
      #pragma unroll
      for (int s=0;s<2;++s){
        int sg=(s<<2)+g;
        bf16x8 bk = ldsr(Tk, rn, sg);
        bf16x8 bs = ldsr(Tsk,rn, sg);
        bf16x8 bq = ldsr(Tsq,rn, sg);
        #pragma unroll
        for (int p=0;p<2;++p){
          smu[p] = mfma16(amq[p][s],  bk, smu[p]);
          ssg[p] = mfma16(acb[p][s],  bs, ssg[p]);
          ssg[p] = mfma16(amk2[p][s], bq, ssg[p]);
        }
      }
      #pragma unroll
      for (int p=0;p<2;++p){
        #pragma unroll
        for (int r=0;r<4;++r){
          float e  = __expf(smu[p][r]*0.125f);
          float wv = e*zl[p][r];
          float u  = wv - wv*wv;
          float sw = u*u*ssg[p][r]*(1.0f/65536.0f);
          int prow = (g<<2)+r, pcol = (t<<4)+l15;
          int a32 = (p<<10) + ((((prow<<3) + ((pcol>>3)^(prow&7)))<<3) + (pcol&7));
          Pu[a32] = cvtpk(wv, sw);         // lo=bf16(w), hi=bf16(Sw)
        }
      }
    }
    __syncthreads();                       // PV tiles + P visible; score reads done
    if (kt < 15){                          // next score tiles fly during PV phase
      long o1 = (long)((kt+1)<<6)*EN;
      gstage(Tk,  khb + o1, EN, w, l);
      gstage(Tsk, skb + o1, EN, w, l);
      gstage(Tsq, sqb + o1, EN, w, l);
    }
    // ---- PV phase ----
    #pragma unroll
    for (int s=0;s<2;++s){
      int sg=(s<<2)+g;
      bf16x8 aw[2], ag[2], pa[2];
      #pragma unroll
      for (int p=0;p<2;++p){
        const u32x4* pp = (const u32x4*)(Pu + (p<<10) + (((l15<<3) + (sg ^ (l15&7)))<<3));
        u32x4 pA = pp[0], pB = pp[1];
        unsigned qa[8] = {pA[0],pA[1],pA[2],pA[3],pB[0],pB[1],pB[2],pB[3]};
        u32x4 awu, agu, pau;
        #pragma unroll
        for (int i2=0;i2<4;++i2){
          unsigned lo = qa[2*i2], hi = qa[2*i2+1];
          awu[i2] = (lo & 0xffffu) | (hi << 16);
          agu[i2] = (lo >> 16) | (hi & 0xffff0000u);
          float w0 = __uint_as_float(lo<<16), g0 = __uint_as_float(lo & 0xffff0000u);
          float w1 = __uint_as_float(hi<<16), g1 = __uint_as_float(hi & 0xffff0000u);
          pau[i2] = cvtpk(fmaf(w0,w0,g0), fmaf(w1,w1,g1));   // w^2 + Sw
        }
        aw[p]=u2b(awu); ag[p]=u2b(agu); pa[p]=u2b(pau);
      }
      #pragma unroll
      for (int t=0;t<4;++t){
        int rn = (t<<4)+l15;
        bf16x8 bm  = ldsr(Tmv,rn,sg);
        bf16x8 bv  = ldsr(Tsv,rn,sg);
        bf16x8 b2m = ldsr(Tm2,rn,sg);
        #pragma unroll
        for (int p=0;p<2;++p){
          accM[p][t] = mfma16(aw[p], bm,  accM[p][t]);
          acc2[p][t] = mfma16(pa[p], bv,  acc2[p][t]);
          acc3[p][t] = mfma16(ag[p], b2m, acc3[p][t]);
        }
      }
    }
  }
  // epilogue
  #pragma unroll
  for (int p=0;p<2;++p){
    long grow0 = bS + q0 + (w<<5) + (p<<4) + (g<<2);
    #pragma unroll
    for (int t=0;t<4;++t){
      int col = (h<<6) + (t<<4) + l15;
      #pragma unroll
      for (int r=0;r<4;++r){
        long o = (grow0 + r)*EN + col;
        muh[o] = f2b(accM[p][t][r]);
        sgh[o] = f2b(sp_f((acc2[p][t][r]+acc3[p][t][r])*(1.0f/1024.0f)));
      }
    }
  }
}

// ---- per-row combined scalar ----
__global__ void k_rows(const u16* __restrict__ muh, const u16* __restrict__ sgh,
                       float* __restrict__ rcomb){
  __shared__ float tmp[4];
  int r = blockIdx.x;
  const u16* m = muh + (long)r*EN;
  const u16* s = sgh + (long)r*EN;
  float s1=0.f, s2=0.f;
  for (int j=threadIdx.x; j<EN; j+=256){ float a=b2f(m[j]); s1+=a*a; s2+=b2f(s[j]); }
  float r1 = blk_reduce(s1, tmp);
  float r2 = blk_reduce(s2, tmp);
  if (threadIdx.x==0) rcomb[r] = r1*(1.0f/589824.0f) + r2*(1.0f/768.0f);
}

// ---- output linear with fused Sigma epilogue; wo^2 precomputed (WT2) ----
__global__ __launch_bounds__(256)
void k_outmm(const u16* __restrict__ muh, const u16* __restrict__ sgh,
             const u16* __restrict__ WTo, const u16* __restrict__ WT2o,
             const float* __restrict__ rcomb, const float* __restrict__ wso,
             float* __restrict__ mu_out, float* __restrict__ sg_out){
  __shared__ __align__(16) u16 lds[16384];
  u16* Am = lds; u16* As = lds + 4096; u16* Bt = lds + 8192; u16* B2t = lds + 12288;
  const int tid = threadIdx.x;
  const int w = tid>>6, l = tid&63, l15 = l&15, g = l>>4;
  const int m0 = blockIdx.y<<6, n0 = blockIdx.x<<6;
  f32x4 accM[4], accS[4];
  #pragma unroll
  for (int t=0;t<4;++t){
    accM[t][0]=0;accM[t][1]=0;accM[t][2]=0;accM[t][3]=0;
    accS[t][0]=0;accS[t][1]=0;accS[t][2]=0;accS[t][3]=0;
  }
  for (int k0=0; k0<EN; k0+=64){
    __syncthreads();
    stage64(Am, muh + (long)m0*EN + k0, EN, tid);
    stage64(As, sgh + (long)m0*EN + k0, EN, tid);
    stage64(Bt, WTo + (long)n0*EN + k0, EN, tid);
    stage64(B2t, WT2o + (long)n0*EN + k0, EN, tid);
    __syncthreads();
    #pragma unroll
    for (int s=0;s<2;++s){
      int sg=(s<<2)+g;
      bf16x8 am = ldsr(Am, (w<<4)+l15, sg);
      bf16x8 as = ldsr(As, (w<<4)+l15, sg);
      #pragma unroll
      for (int t=0;t<4;++t){
        int rn=(t<<4)+l15;
        accM[t] = mfma16(am, ldsr(Bt,rn,sg), accM[t]);
        accS[t] = mfma16(as, ldsr(B2t,rn,sg), accS[t]);
      }
    }
  }
  float rc4[4];
  #pragma unroll
  for (int r=0;r<4;++r) rc4[r] = rcomb[m0 + (w<<4) + (g<<2) + r];
  #pragma unroll
  for (int t=0;t<4;++t){
    int col = n0 + (t<<4) + l15;
    float wsc = wso[col];
    #pragma unroll
    for (int r=0;r<4;++r){
      long row = m0 + (w<<4) + (g<<2) + r;
      mu_out[row*EN + col] = accM[t][r];
      float spre = accS[t][r]*(1.0f/768.0f) + rc4[r]*wsc;
      sg_out[row*EN + col] = sp_f(sp_f(spre));
    }
  }
}

// ---- KL finalize ----
__global__ void k_klf(const float* __restrict__ klacc, float* __restrict__ out){
  float Smu2 = klacc[0], Ssig = klacc[1], Ssp = klacc[2];
  const float C = -5.60517018599f;
  out[0] = 0.5f*(4.f*C - Ssig*(1.0f/768.0f) + Ssp*(1.0f/7.68f) + Smu2*(1.0f/5898.24f));
}

extern "C" void kernel_launch(void* const* d_in, const int* in_sizes, int n_in,
                              void* d_out, int out_size, void* d_ws, size_t ws_size,
                              hipStream_t stream) {
  (void)in_sizes; (void)n_in; (void)out_size; (void)ws_size;
  const float* x      = (const float*)d_in[0];
  const float* wq_mu  = (const float*)d_in[1];
  const float* wq_sig = (const float*)d_in[2];
  const float* wk_mu  = (const float*)d_in[3];
  const float* wk_sig = (const float*)d_in[4];
  const float* wv_mu  = (const float*)d_in[5];
  const float* wv_sig = (const float*)d_in[6];
  const float* wo_mu  = (const float*)d_in[7];
  const float* wo_sig = (const float*)d_in[8];

  char* wsb = (char*)d_ws;
  float* xx    = (float*)(wsb + OFF_XX);
  float* rc    = (float*)(wsb + OFF_RC);
  float* wsig  = (float*)(wsb + OFF_WSIG);
  float* kla   = (float*)(wsb + OFF_KL);
  float* zi    = (float*)(wsb + OFF_ZI);
  u16*   WT    = (u16*)(wsb + OFF_WT);
  u16*   qh    = (u16*)(wsb + OFF_QH);
  u16*   kh    = (u16*)(wsb + OFF_KH);
  u16*   sqd   = (u16*)(wsb + OFF_SQD);
  u16*   skd   = (u16*)(wsb + OFF_SKD);
  u16*   mvT   = (u16*)(wsb + OFF_MVT);
  u16*   mv2T  = (u16*)(wsb + OFF_MV2);
  u16*   svT   = (u16*)(wsb + OFF_SVT);
  u16*   muh   = (u16*)(wsb + OFF_MUH);
  u16*   sgh   = (u16*)(wsb + OFF_SGH);
  u16*   WT2   = (u16*)(wsb + OFF_WT2);

  float* mu_out = (float*)d_out;
  float* sg_out = mu_out + BSE;
  float* kl_out = mu_out + 2*BSE;

  (void)hipMemsetAsync(kla, 0, 3*sizeof(float), stream);
  k_prep<<<4, 256, 0, stream>>>(wq_sig, wk_sig, wv_sig, wo_sig, wsig, kla);
  k_xx<<<BSN, 256, 0, stream>>>(x, xx);
  k_mu2<<<dim3(64,4), 256, 0, stream>>>(wq_mu, wk_mu, wv_mu, wo_mu, kla);
  k_wt<<<dim3(12,12,4), 256, 0, stream>>>(wq_mu, wk_mu, wv_mu, wo_mu, WT, WT2);
  k_sigarr<<<BSN, 256, 0, stream>>>(xx, wsig, sqd, skd);
  k_svt<<<dim3(16,HN,4), 256, 0, stream>>>(xx, wsig, svT);
  k_projmm<<<dim3(12,64,3), 256, 0, stream>>>(x, WT, qh, kh, mvT, mv2T);
  k_z<<<384, 512, 0, stream>>>(qh, kh, zi);

  const int attn_lds = 81920;
  (void)hipFuncSetAttribute((const void*)k_attn,
                      hipFuncAttributeMaxDynamicSharedMemorySize, attn_lds);
  k_attn<<<384, 256, attn_lds, stream>>>(qh, kh, sqd, skd, mvT, svT,
                                         mv2T, zi, muh, sgh);
  k_rows<<<BSN, 256, 0, stream>>>(muh, sgh, rc);
  k_outmm<<<dim3(12,64), 256, 0, stream>>>(muh, sgh, WT + 3l*589824, WT2, rc,
                                           wsig + 3*EN, mu_out, sg_out);
  k_klf<<<1, 1, 0, stream>>>(kla, kl_out);
}

// Round 10
// 316.779 us; speedup vs baseline: 7.6359x; 1.0783x over previous
//
#include <hip/hip_runtime.h>
#include <math.h>

#define EN 768
#define SN 1024
#define HN 12
#define BSN 4096
#define BSE 3145728

#define AS1 __attribute__((address_space(1)))
#define AS3 __attribute__((address_space(3)))

typedef __attribute__((ext_vector_type(8))) short bf16x8;
typedef __attribute__((ext_vector_type(4))) float f32x4;
typedef __attribute__((ext_vector_type(4))) unsigned short u16x4;
typedef __attribute__((ext_vector_type(4))) unsigned int u32x4;
typedef unsigned short u16;

// ---- workspace byte offsets ----
#define OFF_XX   0u
#define OFF_RC   16384u
#define OFF_WSIG 32768u
#define OFF_KL   45056u
#define OFF_ZI   49152u       // [4*12*1024] f32 zinv
#define OFF_WT   262144u      // 4 * 768*768 u16
#define OFF_QH   4980736u
#define OFF_KH   11272192u
#define OFF_SQD  17563648u    // sp(xx*wsq)/2^22 bf16
#define OFF_SKD  23855104u    // sp(xx*wsk)/2^22 bf16
#define OFF_MVT  30146560u
#define OFF_MV2  36438016u
#define OFF_SVT  42729472u
#define OFF_MUH  49020928u    // also hosts xb16 before k_attn runs
#define OFF_SGH  55312384u
#define OFF_WT2  61603840u    // 768*768 u16 (wo^2 bf16)

// scale folded into skd/sqd: 1/64/65536 = 2^-22
#define SSCL 2.384185791015625e-7f
#define SINV 4194304.0f   // 2^22 * ... A-side sq compensation: *64*65536

__device__ __forceinline__ float sp_f(float x){
  return fmaxf(x, 0.f) + log1pf(__expf(-fabsf(x)));
}
__device__ __forceinline__ u16 f2b(float f){
  unsigned u = __float_as_uint(f);
  return (u16)((u + 0x7fffu + ((u>>16)&1u)) >> 16);
}
__device__ __forceinline__ float b2f(u16 h){
  return __uint_as_float(((unsigned)h)<<16);
}
__device__ __forceinline__ unsigned cvtpk(float lo, float hi){
  unsigned r;
  asm("v_cvt_pk_bf16_f32 %0, %1, %2" : "=v"(r) : "v"(lo), "v"(hi));
  return r;
}
__device__ __forceinline__ bf16x8 u2b(u32x4 v){
  union{u32x4 u; bf16x8 b;} x; x.u = v; return x.b;
}
__device__ __forceinline__ f32x4 mfma16(bf16x8 a, bf16x8 b, f32x4 c){
  return __builtin_amdgcn_mfma_f32_16x16x32_bf16(a, b, c, 0, 0, 0);
}
// LDS frag read from swizzled [rows][64] bf16 tile
__device__ __forceinline__ bf16x8 ldsr(const u16* t, int row, int sg){
  int a16 = (row<<3) + (sg ^ (row&7));
  return *(const bf16x8*)(t + (a16<<3));
}
// stage 64x64 bf16 tile with 256 threads (2 slots/thread) via registers
__device__ __forceinline__ void stage64(u16* dst, const u16* src, int rstride, int tid){
  #pragma unroll
  for (int it=0; it<2; ++it){
    int idx = (it<<8) + tid;
    int row = idx>>3, seg = idx&7;
    bf16x8 v = *(const bf16x8*)(src + (long)row*rstride + (seg<<3));
    int a16 = (row<<3) + (seg ^ (row&7));
    *(bf16x8*)(dst + (a16<<3)) = v;
  }
}
// stage 64x64 bf16 tile via global_load_lds; swizzle via per-lane global src
__device__ __forceinline__ void gstage(u16* ltile, const u16* gsrc, long rstride,
                                       int w, int l){
  #pragma unroll
  for (int i=0;i<2;++i){
    int slot = (i<<8) + (w<<6) + l;
    int row  = slot >> 3;
    int seg  = (slot & 7) ^ (row & 7);
    const u16* g = gsrc + (long)row*rstride + (seg<<3);
    u16* d = ltile + (((i<<8) + (w<<6))<<3);
    __builtin_amdgcn_global_load_lds((AS1 void*)g, (AS3 void*)d, 16, 0, 0);
  }
}

__device__ __forceinline__ float blk_reduce(float v, float* tmp){
  #pragma unroll
  for (int off = 32; off; off >>= 1) v += __shfl_down(v, off, 64);
  int w = threadIdx.x >> 6;
  if ((threadIdx.x & 63) == 0) tmp[w] = v;
  __syncthreads();
  float r = 0.f;
  if (threadIdx.x == 0) r = tmp[0] + tmp[1] + tmp[2] + tmp[3];
  __syncthreads();
  return r;
}

// ---- softplus(w_sigma) + KL sigma terms ----
__global__ void k_prep(const float* __restrict__ s0, const float* __restrict__ s1,
                       const float* __restrict__ s2, const float* __restrict__ s3,
                       float* __restrict__ wsig, float* __restrict__ klacc){
  __shared__ float tmp[4];
  const float* src = (blockIdx.x==0)?s0:(blockIdx.x==1)?s1:(blockIdx.x==2)?s2:s3;
  int l = blockIdx.x;
  float ssum=0.f, spsum=0.f;
  for (int j=threadIdx.x; j<EN; j+=256){
    float sg = src[j];
    float w  = log1pf(__expf(sg));
    wsig[l*EN+j] = w;
    ssum += sg; spsum += w;
  }
  float a = blk_reduce(ssum, tmp);
  float b = blk_reduce(spsum, tmp);
  if (threadIdx.x==0){ atomicAdd(&klacc[1], a); atomicAdd(&klacc[2], b); }
}

// ---- per-row: xx[r], bf16(x), sq/2^22, sk/2^22 ----
__global__ void k_xxs(const float* __restrict__ x, const float* __restrict__ wsig,
                      float* __restrict__ xx, u16* __restrict__ xb,
                      u16* __restrict__ sqd, u16* __restrict__ skd){
  __shared__ float tmp[4];
  __shared__ float srow[EN];
  __shared__ float sxx;
  int r = blockIdx.x, tid = threadIdx.x;
  const float* xr = x + (long)r*EN;
  float s=0.f;
  #pragma unroll
  for (int it=0; it<3; ++it){
    int j = it*256 + tid;
    float v = xr[j];
    srow[j] = v;
    s += v*v;
  }
  float t = blk_reduce(s, tmp);
  if (tid==0){ float v = t*(1.0f/589824.0f); xx[r]=v; sxx=v; }
  __syncthreads();
  float xv = sxx;
  #pragma unroll
  for (int it=0; it<3; ++it){
    int c = it*256 + tid;
    xb[(long)r*EN+c]  = f2b(srow[c]);
    sqd[(long)r*EN+c] = f2b(sp_f(xv*wsig[c])*SSCL);
    skd[(long)r*EN+c] = f2b(sp_f(xv*wsig[EN+c])*SSCL);
  }
}

// ---- transpose weights to bf16 + mu^2 KL accumulation; z=3 also wo^2 ----
__global__ void k_wt(const float* __restrict__ w0, const float* __restrict__ w1,
                     const float* __restrict__ w2, const float* __restrict__ w3,
                     u16* __restrict__ wt, u16* __restrict__ wt2,
                     float* __restrict__ klacc){
  __shared__ float t[64*65];
  __shared__ float tmp[4];
  const float* W = (blockIdx.z==0)?w0:(blockIdx.z==1)?w1:(blockIdx.z==2)?w2:w3;
  u16* WT = wt + (long)blockIdx.z*589824;
  int r0 = blockIdx.y<<6, c0 = blockIdx.x<<6;
  int tid = threadIdx.x;
  float s = 0.f;
  #pragma unroll
  for (int it=0; it<16; ++it){
    int idx=(it<<8)+tid; int r=idx>>6, c=idx&63;
    float v = W[(long)(r0+r)*EN + c0+c];
    t[c*65+r] = v;
    s += v*v;
  }
  float sr = blk_reduce(s, tmp);
  if (tid==0) atomicAdd(&klacc[0], sr);
  #pragma unroll
  for (int it=0; it<16; ++it){
    int idx=(it<<8)+tid; int c=idx>>6, r=idx&63;
    u16 bb = f2b(t[c*65+r]);
    WT[(long)(c0+c)*EN + r0+r] = bb;
    if (blockIdx.z == 3){
      float bf = b2f(bb);
      wt2[(long)(c0+c)*EN + r0+r] = f2b(bf*bf);
    }
  }
}

// ---- svT[b,h][d][k] = softplus(xx[b,k]*wsig_v[h,d]) ----
__global__ void k_svt(const float* __restrict__ xx, const float* __restrict__ wsig,
                      u16* __restrict__ svT){
  __shared__ float sxx[64], swv[64];
  int kt=blockIdx.x, h=blockIdx.y, b=blockIdx.z, tid=threadIdx.x;
  if (tid < 64){
    sxx[tid] = xx[(long)b*SN + (kt<<6) + tid];
    swv[tid] = wsig[2*EN + (h<<6) + tid];
  }
  __syncthreads();
  long obase = (((long)(b*HN+h))<<6)*SN + (kt<<6);
  #pragma unroll
  for (int it=0; it<16; ++it){
    int idx=(it<<8)+tid; int d=idx>>6, k=idx&63;
    svT[obase + (long)d*SN + k] = f2b(sp_f(sxx[k]*swv[d]));
  }
}

// ---- projections via MFMA (gstage staging); z=2 writes transposed mvT+mv2T ----
__global__ __launch_bounds__(256)
void k_projmm(const u16* __restrict__ xb, const u16* __restrict__ WT,
              u16* __restrict__ oq, u16* __restrict__ ok,
              u16* __restrict__ mvT, u16* __restrict__ mv2T){
  __shared__ __align__(16) u16 lds[8192];
  u16* At = lds; u16* Bt = lds + 4096;
  const int tid = threadIdx.x;
  const int w = tid>>6, l = tid&63, l15 = l&15, g = l>>4;
  const int m0 = blockIdx.y<<6, n0 = blockIdx.x<<6;
  const u16* Wt = WT + (long)blockIdx.z*589824;
  f32x4 acc[4];
  #pragma unroll
  for (int t=0;t<4;++t){ acc[t][0]=0;acc[t][1]=0;acc[t][2]=0;acc[t][3]=0; }
  for (int k0=0; k0<EN; k0+=64){
    __syncthreads();
    gstage(At, xb + (long)m0*EN + k0, EN, w, l);
    gstage(Bt, Wt + (long)n0*EN + k0, EN, w, l);
    __syncthreads();
    #pragma unroll
    for (int s=0;s<2;++s){
      int sg=(s<<2)+g;
      bf16x8 af = ldsr(At, (w<<4)+l15, sg);
      #pragma unroll
      for (int t=0;t<4;++t)
        acc[t] = mfma16(af, ldsr(Bt,(t<<4)+l15,sg), acc[t]);
    }
  }
  if (blockIdx.z < 2){
    u16* out = blockIdx.z ? ok : oq;
    #pragma unroll
    for (int t=0;t<4;++t){
      int col = n0 + (t<<4) + l15;
      #pragma unroll
      for (int r=0;r<4;++r){
        long row = m0 + (w<<4) + (g<<2) + r;
        out[row*EN + col] = f2b(acc[t][r]);
      }
    }
  } else {
    int b  = m0 >> 10;
    int hh = n0 >> 6;
    long obase = (((long)(b*HN+hh))<<6)*SN;
    int tok0 = (m0 & 1023) + (w<<4) + (g<<2);
    #pragma unroll
    for (int t=0;t<4;++t){
      int d = (t<<4) + l15;
      u16x4 m4, s4;
      #pragma unroll
      for (int r=0;r<4;++r){
        u16 mb = f2b(acc[t][r]);
        m4[r] = mb;
        float mf = b2f(mb);
        s4[r] = f2b(mf*mf);
      }
      *(u16x4*)&mvT[obase + (long)d*SN + tok0]  = m4;
      *(u16x4*)&mv2T[obase + (long)d*SN + tok0] = s4;
    }
  }
}

// ---- Z kernel: barrier-free, B-frags read directly from global (L2-hot) ----
__global__ __launch_bounds__(256)
void k_z(const u16* __restrict__ qh, const u16* __restrict__ kh,
         float* __restrict__ zi){
  const int tid = threadIdx.x;
  const int w = tid>>6, l = tid&63, l15 = l&15, g = l>>4;
  // 768 blocks = 8 XCDs x 6 pairs x 16 q-tiles(64)
  const int i = blockIdx.x;
  const int xcd = i & 7, slot = i >> 3;
  const int qt = slot & 15;
  const int pair = xcd*6 + (slot >> 4);
  const int h = pair % HN, b = pair / HN;
  const int q0 = (qt<<6) + (w<<4);
  const long bS = (long)b*SN;
  bf16x8 amq[2];
  {
    long qrow = (bS + q0 + l15) * EN;
    #pragma unroll
    for (int s=0;s<2;++s)
      amq[s] = *(const bf16x8*)(qh + qrow + (h<<6) + (s<<5) + (g<<3));
  }
  const u16* khb = kh + bS*EN + (h<<6);
  f32x4 zacc = {0.f,0.f,0.f,0.f};
  for (int kt=0; kt<16; ++kt){
    #pragma unroll
    for (int t=0;t<4;++t){
      f32x4 sm = {0.f,0.f,0.f,0.f};
      #pragma unroll
      for (int s=0;s<2;++s){
        const bf16x8 bf = *(const bf16x8*)(khb + (long)((kt<<6)+(t<<4)+l15)*EN
                                           + (((s<<2)+g)<<3));
        sm = mfma16(amq[s], bf, sm);
      }
      #pragma unroll
      for (int r=0;r<4;++r) zacc[r] += __expf(sm[r]*0.125f);
    }
  }
  #pragma unroll
  for (int m=1; m<16; m<<=1){
    #pragma unroll
    for (int r=0;r<4;++r) zacc[r] += __shfl_xor(zacc[r], m, 64);
  }
  if (l15 == 0){
    long zbase = (((long)(b*HN+h))<<10) + q0 + (g<<2);
    #pragma unroll
    for (int r=0;r<4;++r) zi[zbase + r] = 1.0f/zacc[r];
  }
}

// ---- fused Bayesian attention; 4 waves, M=32/wave, q-tile 128, 80KB LDS,
//      gstage split-phase pipeline, conflict-free P writes, fused row sums ----
__global__ __launch_bounds__(256, 2)
void k_attn(const u16* __restrict__ qh, const u16* __restrict__ kh,
            const u16* __restrict__ sqd, const u16* __restrict__ skd,
            const u16* __restrict__ mvT, const u16* __restrict__ svT,
            const u16* __restrict__ mv2T, const float* __restrict__ zi,
            u16* __restrict__ muh, u16* __restrict__ sgh,
            float* __restrict__ rc){
  extern __shared__ u16 lds2[];
  u16* Tk  = lds2;
  u16* Tsk = lds2 + 4096;
  u16* Tsq = lds2 + 8192;
  u16* Tmv = lds2 + 12288;
  u16* Tsv = lds2 + 16384;
  u16* Tm2 = lds2 + 20480;
  const int tid = threadIdx.x;
  const int w = tid>>6, l = tid&63, l15 = l&15, g = l>>4;
  unsigned* Pu = (unsigned*)(lds2 + 24576) + (w<<11);   // 8KB/wave, 2 strips
  const int ib = blockIdx.x;
  const int xcd = ib & 7, slot = ib >> 3;
  const int qt = slot & 7;
  const int pair = xcd*6 + (slot >> 3);
  const int h = pair % HN, b = pair / HN;
  const int q0 = qt<<7;
  const long bS = (long)b*SN;

  // constant A-fragments: 2 strips of 16 q-rows per wave (M=32)
  bf16x8 amq[2][2], acb[2][2], amk2[2][2];
  #pragma unroll
  for (int p=0;p<2;++p){
    long qrow = (bS + q0 + (w<<5) + (p<<4) + l15) * EN;
    #pragma unroll
    for (int s=0;s<2;++s){
      int eoff = (h<<6) + (s<<5) + (g<<3);
      bf16x8 q8 = *(const bf16x8*)(qh + qrow + eoff);
      bf16x8 k8 = *(const bf16x8*)(kh + qrow + eoff);
      bf16x8 s8 = *(const bf16x8*)(sqd + qrow + eoff);
      amq[p][s] = q8;
      bf16x8 t2, tc;
      #pragma unroll
      for (int j=0;j<8;++j){
        float kv = b2f((u16)k8[j]);
        t2[j] = (short)f2b(kv*kv);
        float qv = b2f((u16)q8[j]);
        float sv = b2f((u16)s8[j]) * SINV;        // undo 2^-22 folding
        tc[j] = (short)f2b(qv*qv + sv);
      }
      amk2[p][s] = t2; acb[p][s] = tc;
    }
  }
  f32x4 zl[2];
  #pragma unroll
  for (int p=0;p<2;++p){
    long zbase = (((long)(b*HN+h))<<10) + q0 + (w<<5) + (p<<4) + (g<<2);
    #pragma unroll
    for (int r=0;r<4;++r) zl[p][r] = zi[zbase + r];
  }

  const u16* khb = kh  + bS*EN + (h<<6);
  const u16* skb = skd + bS*EN + (h<<6);
  const u16* sqb = sqd + bS*EN + (h<<6);
  const long hb64 = ((long)(b*HN+h))<<6;
  const u16* mvb = mvT  + hb64*SN;
  const u16* svb = svT  + hb64*SN;
  const u16* m2b = mv2T + hb64*SN;

  f32x4 accM[2][4], acc2[2][4], acc3[2][4];
  #pragma unroll
  for (int p=0;p<2;++p)
    #pragma unroll
    for (int t=0;t<4;++t){
      accM[p][t][0]=0;accM[p][t][1]=0;accM[p][t][2]=0;accM[p][t][3]=0;
      acc2[p][t][0]=0;acc2[p][t][1]=0;acc2[p][t][2]=0;acc2[p][t][3]=0;
      acc3[p][t][0]=0;acc3[p][t][1]=0;acc3[p][t][2]=0;acc3[p][t][3]=0;
    }

  // prologue: stage score tiles for kt=0
  gstage(Tk,  khb, EN, w, l);
  gstage(Tsk, skb, EN, w, l);
  gstage(Tsq, sqb, EN, w, l);

  for (int kt=0; kt<16; ++kt){
    __syncthreads();
    gstage(Tmv, mvb + (kt<<6), SN, w, l);
    gstage(Tsv, svb + (kt<<6), SN, w, l);
    gstage(Tm2, m2b + (kt<<6), SN, w, l);

    // ---- score phase ----
    #pragma unroll
    for (int t=0;t<4;++t){
      f32x4 smu[2], ssg[2];
      #pragma unroll
      for (int p=0;p<2;++p){
        smu[p][0]=0;smu[p][1]=0;smu[p][2]=0;smu[p][3]=0;
        ssg[p][0]=0;ssg[p][1]=0;ssg[p][2]=0;ssg[p][3]=0;
      }
      int rn = (t<<4)+l15;
      #pragma unroll
      for (int s=0;s<2;++s){
        int sg=(s<<2)+g;
        bf16x8 bk = ldsr(Tk, rn, sg);
        bf16x8 bs = ldsr(Tsk,rn, sg);
        bf16x8 bq = ldsr(Tsq,rn, sg);
        #pragma unroll
        for (int p=0;p<2;++p){
          smu[p] = mfma16(amq[p][s],  bk, smu[p]);
          ssg[p] = mfma16(acb[p][s],  bs, ssg[p]);
          ssg[p] = mfma16(amk2[p][s], bq, ssg[p]);
        }
      }
      // P layout: a32 = [p|pc3|r|g|pl] -> write bank (g<<3)|pl: conflict-free
      #pragma unroll
      for (int p=0;p<2;++p){
        #pragma unroll
        for (int r=0;r<4;++r){
          float e  = __expf(smu[p][r]*0.125f);
          float wv = e*zl[p][r];
          float u  = wv - wv*wv;
          float sw = u*u*ssg[p][r];                 // /2^22 folded in arrays
          int pc3 = (t<<1) + (l15>>3);
          int a32 = (p<<10) | (pc3<<7) | (r<<5) | (g<<3) | (l15&7);
          Pu[a32] = cvtpk(wv, sw);
        }
      }
    }
    __syncthreads();
    if (kt < 15){
      long o1 = (long)((kt+1)<<6)*EN;
      gstage(Tk,  khb + o1, EN, w, l);
      gstage(Tsk, skb + o1, EN, w, l);
      gstage(Tsq, sqb + o1, EN, w, l);
    }
    // ---- PV phase ----
    #pragma unroll
    for (int s=0;s<2;++s){
      int sg=(s<<2)+g;
      bf16x8 aw[2], ag[2], pa[2];
      #pragma unroll
      for (int p=0;p<2;++p){
        const u32x4* pp = (const u32x4*)(Pu + ((p<<10) | (sg<<7) |
                            ((l15&3)<<5) | ((l15>>2)<<3)));
        u32x4 pA = pp[0], pB = pp[1];
        unsigned qa[8] = {pA[0],pA[1],pA[2],pA[3],pB[0],pB[1],pB[2],pB[3]};
        u32x4 awu, agu, pau;
        #pragma unroll
        for (int i2=0;i2<4;++i2){
          unsigned lo = qa[2*i2], hi = qa[2*i2+1];
          awu[i2] = (lo & 0xffffu) | (hi << 16);
          agu[i2] = (lo >> 16) | (hi & 0xffff0000u);
          float w0 = __uint_as_float(lo<<16), g0 = __uint_as_float(lo & 0xffff0000u);
          float w1 = __uint_as_float(hi<<16), g1 = __uint_as_float(hi & 0xffff0000u);
          pau[i2] = cvtpk(fmaf(w0,w0,g0), fmaf(w1,w1,g1));   // w^2 + Sw
        }
        aw[p]=u2b(awu); ag[p]=u2b(agu); pa[p]=u2b(pau);
      }
      #pragma unroll
      for (int t=0;t<4;++t){
        int rn = (t<<4)+l15;
        bf16x8 bm  = ldsr(Tmv,rn,sg);
        bf16x8 bv  = ldsr(Tsv,rn,sg);
        bf16x8 b2m = ldsr(Tm2,rn,sg);
        #pragma unroll
        for (int p=0;p<2;++p){
          accM[p][t] = mfma16(aw[p], bm,  accM[p][t]);
          acc2[p][t] = mfma16(pa[p], bv,  acc2[p][t]);
          acc3[p][t] = mfma16(ag[p], b2m, acc3[p][t]);
        }
      }
    }
  }
  // epilogue: store + fused per-row partial sums (rcomb)
  #pragma unroll
  for (int p=0;p<2;++p){
    long grow0 = bS + q0 + (w<<5) + (p<<4) + (g<<2);
    float sm2[4] = {0.f,0.f,0.f,0.f};
    float ssm[4] = {0.f,0.f,0.f,0.f};
    #pragma unroll
    for (int t=0;t<4;++t){
      int col = (h<<6) + (t<<4) + l15;
      #pragma unroll
      for (int r=0;r<4;++r){
        long o = (grow0 + r)*EN + col;
        float m = accM[p][t][r];
        float sv = sp_f((acc2[p][t][r]+acc3[p][t][r])*(1.0f/1024.0f));
        muh[o] = f2b(m);
        sgh[o] = f2b(sv);
        sm2[r] += m*m;
        ssm[r] += sv;
      }
    }
    #pragma unroll
    for (int r=0;r<4;++r){
      float a = sm2[r], c = ssm[r];
      #pragma unroll
      for (int off=1; off<16; off<<=1){
        a += __shfl_xor(a, off, 16);
        c += __shfl_xor(c, off, 16);
      }
      if (l15 == 0)
        atomicAdd(&rc[grow0 + r], a*(1.0f/589824.0f) + c*(1.0f/768.0f));
    }
  }
}

// ---- output linear with fused Sigma epilogue; wo^2 precomputed (WT2) ----
__global__ __launch_bounds__(256)
void k_outmm(const u16* __restrict__ muh, const u16* __restrict__ sgh,
             const u16* __restrict__ WTo, const u16* __restrict__ WT2o,
             const float* __restrict__ rcomb, const float* __restrict__ wso,
             float* __restrict__ mu_out, float* __restrict__ sg_out){
  __shared__ __align__(16) u16 lds[16384];
  u16* Am = lds; u16* As = lds + 4096; u16* Bt = lds + 8192; u16* B2t = lds + 12288;
  const int tid = threadIdx.x;
  const int w = tid>>6, l = tid&63, l15 = l&15, g = l>>4;
  const int m0 = blockIdx.y<<6, n0 = blockIdx.x<<6;
  f32x4 accM[4], accS[4];
  #pragma unroll
  for (int t=0;t<4;++t){
    accM[t][0]=0;accM[t][1]=0;accM[t][2]=0;accM[t][3]=0;
    accS[t][0]=0;accS[t][1]=0;accS[t][2]=0;accS[t][3]=0;
  }
  for (int k0=0; k0<EN; k0+=64){
    __syncthreads();
    gstage(Am, muh + (long)m0*EN + k0, EN, w, l);
    gstage(As, sgh + (long)m0*EN + k0, EN, w, l);
    gstage(Bt, WTo + (long)n0*EN + k0, EN, w, l);
    gstage(B2t, WT2o + (long)n0*EN + k0, EN, w, l);
    __syncthreads();
    #pragma unroll
    for (int s=0;s<2;++s){
      int sg=(s<<2)+g;
      bf16x8 am = ldsr(Am, (w<<4)+l15, sg);
      bf16x8 as = ldsr(As, (w<<4)+l15, sg);
      #pragma unroll
      for (int t=0;t<4;++t){
        int rn=(t<<4)+l15;
        accM[t] = mfma16(am, ldsr(Bt,rn,sg), accM[t]);
        accS[t] = mfma16(as, ldsr(B2t,rn,sg), accS[t]);
      }
    }
  }
  float rc4[4];
  #pragma unroll
  for (int r=0;r<4;++r) rc4[r] = rcomb[m0 + (w<<4) + (g<<2) + r];
  #pragma unroll
  for (int t=0;t<4;++t){
    int col = n0 + (t<<4) + l15;
    float wsc = wso[col];
    #pragma unroll
    for (int r=0;r<4;++r){
      long row = m0 + (w<<4) + (g<<2) + r;
      mu_out[row*EN + col] = accM[t][r];
      float spre = accS[t][r]*(1.0f/768.0f) + rc4[r]*wsc;
      sg_out[row*EN + col] = sp_f(sp_f(spre));
    }
  }
}

// ---- KL finalize ----
__global__ void k_klf(const float* __restrict__ klacc, float* __restrict__ out){
  float Smu2 = klacc[0], Ssig = klacc[1], Ssp = klacc[2];
  const float C = -5.60517018599f;
  out[0] = 0.5f*(4.f*C - Ssig*(1.0f/768.0f) + Ssp*(1.0f/7.68f) + Smu2*(1.0f/5898.24f));
}

extern "C" void kernel_launch(void* const* d_in, const int* in_sizes, int n_in,
                              void* d_out, int out_size, void* d_ws, size_t ws_size,
                              hipStream_t stream) {
  (void)in_sizes; (void)n_in; (void)out_size; (void)ws_size;
  const float* x      = (const float*)d_in[0];
  const float* wq_mu  = (const float*)d_in[1];
  const float* wq_sig = (const float*)d_in[2];
  const float* wk_mu  = (const float*)d_in[3];
  const float* wk_sig = (const float*)d_in[4];
  const float* wv_mu  = (const float*)d_in[5];
  const float* wv_sig = (const float*)d_in[6];
  const float* wo_mu  = (const float*)d_in[7];
  const float* wo_sig = (const float*)d_in[8];

  char* wsb = (char*)d_ws;
  float* xx    = (float*)(wsb + OFF_XX);
  float* rc    = (float*)(wsb + OFF_RC);
  float* wsig  = (float*)(wsb + OFF_WSIG);
  float* kla   = (float*)(wsb + OFF_KL);
  float* zi    = (float*)(wsb + OFF_ZI);
  u16*   WT    = (u16*)(wsb + OFF_WT);
  u16*   qh    = (u16*)(wsb + OFF_QH);
  u16*   kh    = (u16*)(wsb + OFF_KH);
  u16*   sqd   = (u16*)(wsb + OFF_SQD);
  u16*   skd   = (u16*)(wsb + OFF_SKD);
  u16*   mvT   = (u16*)(wsb + OFF_MVT);
  u16*   mv2T  = (u16*)(wsb + OFF_MV2);
  u16*   svT   = (u16*)(wsb + OFF_SVT);
  u16*   muh   = (u16*)(wsb + OFF_MUH);
  u16*   sgh   = (u16*)(wsb + OFF_SGH);
  u16*   WT2   = (u16*)(wsb + OFF_WT2);
  u16*   xb16  = muh;   // muh region hosts bf16(x) until k_attn overwrites it

  float* mu_out = (float*)d_out;
  float* sg_out = mu_out + BSE;
  float* kl_out = mu_out + 2*BSE;

  (void)hipMemsetAsync(kla, 0, 3*sizeof(float), stream);
  (void)hipMemsetAsync(rc, 0, BSN*sizeof(float), stream);
  k_prep<<<4, 256, 0, stream>>>(wq_sig, wk_sig, wv_sig, wo_sig, wsig, kla);
  k_xxs<<<BSN, 256, 0, stream>>>(x, wsig, xx, xb16, sqd, skd);
  k_wt<<<dim3(12,12,4), 256, 0, stream>>>(wq_mu, wk_mu, wv_mu, wo_mu, WT, WT2, kla);
  k_svt<<<dim3(16,HN,4), 256, 0, stream>>>(xx, wsig, svT);
  k_projmm<<<dim3(12,64,3), 256, 0, stream>>>(xb16, WT, qh, kh, mvT, mv2T);
  k_z<<<768, 256, 0, stream>>>(qh, kh, zi);

  const int attn_lds = 81920;
  (void)hipFuncSetAttribute((const void*)k_attn,
                      hipFuncAttributeMaxDynamicSharedMemorySize, attn_lds);
  k_attn<<<384, 256, attn_lds, stream>>>(qh, kh, sqd, skd, mvT, svT,
                                         mv2T, zi, muh, sgh, rc);
  k_outmm<<<dim3(12,64), 256, 0, stream>>>(muh, sgh, WT + 3l*589824, WT2, rc,
                                           wsig + 3*EN, mu_out, sg_out);
  k_klf<<<1, 1, 0, stream>>>(kla, kl_out);
}